// Round 1
// baseline (18849.677 us; speedup 1.0000x reference)
//
#include <hip/hip_runtime.h>
#include <math.h>

#define NN 32768      // nodes
#define NE 102400     // edges
#define HD 128        // H
#define EED 64        // edge enc dim
#define MSGD 256
#define NG 512        // graphs
#define EPG 200       // edges per graph
#define NP 256        // pairs
#define SKD 32

// ---------------- node encoder: h = nf @ Wn + bn ----------------
__global__ void __launch_bounds__(256) k_enc_node(const float* __restrict__ nf,
    const float* __restrict__ W, const float* __restrict__ b, float* __restrict__ h){
  __shared__ float Ws[16*128];
  int t = threadIdx.x;
  for (int i=t;i<16*128;i+=256) Ws[i]=W[i];
  __syncthreads();
  int node = blockIdx.x*2 + (t>>7);
  int f = t & 127;
  const float* x = nf + node*16;
  float acc = b[f];
  #pragma unroll
  for (int k=0;k<16;k++) acc = fmaf(x[k], Ws[k*128+f], acc);
  h[node*HD+f] = acc;
}

// ---------------- edge encoder: e = ef @ We + be ----------------
__global__ void __launch_bounds__(256) k_enc_edge(const float* __restrict__ ef,
    const float* __restrict__ W, const float* __restrict__ b, float* __restrict__ ee){
  __shared__ float Ws[16*64];
  int t = threadIdx.x;
  for (int i=t;i<16*64;i+=256) Ws[i]=W[i];
  __syncthreads();
  int edge = blockIdx.x*4 + (t>>6);
  int f = t & 63;
  const float* x = ef + edge*16;
  float acc = b[f];
  #pragma unroll
  for (int k=0;k<16;k++) acc = fmaf(x[k], Ws[k*64+f], acc);
  ee[edge*EED+f] = acc;
}

// ---------------- message MLPs (fwd+rev) ----------------
// 16 edges per block, 256 threads (thread = output feature).
// xs = [h[s] | h[d] | e] ; rev input is xs with the two 128-blocks swapped
// (handled by a per-ktile source offset). If FINAL: write e_final = fwd+rev,
// else atomicAdd fwd->agg[to], rev->agg[from].
template<bool FINAL>
__global__ void __launch_bounds__(256,2) k_msg(const float* __restrict__ h,
    const float* __restrict__ ee, const int* __restrict__ from_idx, const int* __restrict__ to_idx,
    const float* __restrict__ w1f, const float* __restrict__ b1f,
    const float* __restrict__ w2f, const float* __restrict__ b2f,
    const float* __restrict__ w1r, const float* __restrict__ b1r,
    const float* __restrict__ w2r, const float* __restrict__ b2r,
    float* __restrict__ outp){
  __shared__ float xs[16][320];   // 20 KB
  __shared__ float y1s[16][256];  // 16 KB
  __shared__ float ws[32*256];    // 32 KB
  __shared__ int sidx[16], didx[16];
  int t = threadIdx.x;
  int e0 = blockIdx.x*16;
  if (t < 16){ sidx[t]=from_idx[e0+t]; didx[t]=to_idx[e0+t]; }
  __syncthreads();
  for (int i=t;i<16*320;i+=256){
    int e = i/320, k = i - e*320;
    float v;
    if (k < 128)      v = h[sidx[e]*HD + k];
    else if (k < 256) v = h[didx[e]*HD + (k-128)];
    else              v = ee[(size_t)(e0+e)*EED + (k-256)];
    xs[e][k] = v;
  }

  for (int dir=0; dir<2; dir++){
    const float* W1 = dir ? w1r : w1f;
    const float* B1 = dir ? b1r : b1f;
    const float* W2 = dir ? w2r : w2f;
    const float* B2 = dir ? b2r : b2f;
    float acc[16];
    {
      float bb = B1[t];
      #pragma unroll
      for (int e=0;e<16;e++) acc[e]=bb;
    }
    // layer 1: K=320 in tiles of 32
    for (int kt=0; kt<10; kt++){
      __syncthreads();
      for (int i=t*4;i<32*256;i+=1024)
        *(float4*)&ws[i] = *(const float4*)&W1[kt*8192 + i];
      __syncthreads();
      int koff = kt*32;
      int src = koff;
      if (dir==1){ if (koff<128) src = koff+128; else if (koff<256) src = koff-128; }
      #pragma unroll 2
      for (int k=0;k<32;k+=4){
        float w0=ws[(k+0)*256+t], w1=ws[(k+1)*256+t], w2=ws[(k+2)*256+t], w3=ws[(k+3)*256+t];
        #pragma unroll
        for (int e=0;e<16;e++){
          const float4 x4 = *(const float4*)&xs[e][src+k];
          acc[e] = fmaf(x4.x,w0, fmaf(x4.y,w1, fmaf(x4.z,w2, fmaf(x4.w,w3, acc[e]))));
        }
      }
    }
    __syncthreads();
    #pragma unroll
    for (int e=0;e<16;e++) y1s[e][t] = fmaxf(acc[e], 0.f);
    float acc2[16];
    {
      float bb = B2[t];
      #pragma unroll
      for (int e=0;e<16;e++) acc2[e]=bb;
    }
    // layer 2: K=256 in tiles of 32
    for (int kt=0; kt<8; kt++){
      __syncthreads();
      for (int i=t*4;i<32*256;i+=1024)
        *(float4*)&ws[i] = *(const float4*)&W2[kt*8192 + i];
      __syncthreads();
      int koff = kt*32;
      #pragma unroll 2
      for (int k=0;k<32;k+=4){
        float w0=ws[(k+0)*256+t], w1=ws[(k+1)*256+t], w2=ws[(k+2)*256+t], w3=ws[(k+3)*256+t];
        #pragma unroll
        for (int e=0;e<16;e++){
          const float4 x4 = *(const float4*)&y1s[e][koff+k];
          acc2[e] = fmaf(x4.x,w0, fmaf(x4.y,w1, fmaf(x4.z,w2, fmaf(x4.w,w3, acc2[e]))));
        }
      }
    }
    if (FINAL){
      if (dir==0){
        #pragma unroll
        for (int e=0;e<16;e++) outp[(size_t)(e0+e)*MSGD + t] = acc2[e];
      } else {
        #pragma unroll
        for (int e=0;e<16;e++) outp[(size_t)(e0+e)*MSGD + t] += acc2[e];
      }
    } else {
      if (dir==0){
        #pragma unroll
        for (int e=0;e<16;e++) atomicAdd(&outp[(size_t)didx[e]*MSGD + t], acc2[e]);
      } else {
        #pragma unroll
        for (int e=0;e<16;e++) atomicAdd(&outp[(size_t)sidx[e]*MSGD + t], acc2[e]);
      }
    }
    __syncthreads();  // protect y1s/ws before next dir
  }
}

// ---------------- GRU: gi=agg@Wih+bih, gh=h@Whh+bhh, gate update ----------------
// 384 threads (thread = gate column), 16 nodes per block.
__global__ void __launch_bounds__(384,3) k_gru(const float* __restrict__ h,
    const float* __restrict__ agg,
    const float* __restrict__ Wih, const float* __restrict__ bih,
    const float* __restrict__ Whh, const float* __restrict__ bhh,
    float* __restrict__ hnew){
  __shared__ float as[16][256];   // 16 KB
  __shared__ float hs[16][128];   // 8 KB
  __shared__ float gis[16][384];  // 24 KB
  __shared__ float ghs[16][384];  // 24 KB
  int t = threadIdx.x;
  int n0 = blockIdx.x*16;
  for (int i=t;i<16*256;i+=384) as[0][i]=agg[(size_t)n0*256 + i];
  for (int i=t;i<16*128;i+=384) hs[0][i]=h[(size_t)n0*128 + i];
  __syncthreads();
  float gi[16], gh[16];
  {
    float bi=bih[t], bh=bhh[t];
    #pragma unroll
    for (int n=0;n<16;n++){ gi[n]=bi; gh[n]=bh; }
  }
  for (int k=0;k<256;k+=4){
    float w0=Wih[(k+0)*384+t], w1=Wih[(k+1)*384+t], w2=Wih[(k+2)*384+t], w3=Wih[(k+3)*384+t];
    #pragma unroll
    for (int n=0;n<16;n++){
      const float4 a4 = *(const float4*)&as[n][k];
      gi[n] = fmaf(a4.x,w0, fmaf(a4.y,w1, fmaf(a4.z,w2, fmaf(a4.w,w3, gi[n]))));
    }
  }
  for (int k=0;k<128;k+=4){
    float w0=Whh[(k+0)*384+t], w1=Whh[(k+1)*384+t], w2=Whh[(k+2)*384+t], w3=Whh[(k+3)*384+t];
    #pragma unroll
    for (int n=0;n<16;n++){
      const float4 h4 = *(const float4*)&hs[n][k];
      gh[n] = fmaf(h4.x,w0, fmaf(h4.y,w1, fmaf(h4.z,w2, fmaf(h4.w,w3, gh[n]))));
    }
  }
  #pragma unroll
  for (int n=0;n<16;n++){ gis[n][t]=gi[n]; ghs[n][t]=gh[n]; }
  __syncthreads();
  for (int i=t;i<16*128;i+=384){
    int n = i>>7, f = i&127;
    float r = 1.f/(1.f + __expf(-(gis[n][f]      + ghs[n][f])));
    float z = 1.f/(1.f + __expf(-(gis[n][128+f]  + ghs[n][128+f])));
    float nn = tanhf(gis[n][256+f] + r*ghs[n][256+f]);
    hnew[(size_t)(n0+n)*128 + f] = (1.f - z)*nn + z*hs[n][f];
  }
}

// ---------------- SK transform: t_all[g][i][0:32], rows>=200 zeroed ----------------
__global__ void __launch_bounds__(256) k_tall(const float* __restrict__ ef,
    const float* __restrict__ W1, const float* __restrict__ b1,
    const float* __restrict__ W2, const float* __restrict__ b2,
    float* __restrict__ tall){
  __shared__ float W1s[256*32];
  __shared__ float W2s[32*32];
  __shared__ float b1s[32], b2s[32];
  __shared__ float xsr[8][256];
  __shared__ float y1s[8][32];
  int t = threadIdx.x;
  for (int i=t;i<256*32;i+=256) W1s[i]=W1[i];
  for (int i=t;i<32*32;i+=256)  W2s[i]=W2[i];
  if (t<32){ b1s[t]=b1[t]; b2s[t]=b2[t]; }
  int g = blockIdx.x >> 5;
  int i0 = (blockIdx.x & 31)*8;
  for (int i=t;i<8*256;i+=256){
    int r = i>>8, k = i&255;
    int row = i0+r;
    xsr[r][k] = (row < EPG) ? ef[((size_t)g*EPG + row)*MSGD + k] : 0.f;
  }
  __syncthreads();
  int r = t>>5, c = t&31;
  float acc = b1s[c];
  for (int k=0;k<256;k+=4){
    const float4 x4 = *(const float4*)&xsr[r][k];
    acc = fmaf(x4.x,W1s[(k+0)*32+c], fmaf(x4.y,W1s[(k+1)*32+c],
          fmaf(x4.z,W1s[(k+2)*32+c], fmaf(x4.w,W1s[(k+3)*32+c], acc))));
  }
  y1s[r][c] = fmaxf(acc, 0.f);
  __syncthreads();
  float acc2 = b2s[c];
  #pragma unroll
  for (int k=0;k<32;k++) acc2 = fmaf(y1s[r][k], W2s[k*32+c], acc2);
  int row = i0+r;
  tall[((size_t)g*256 + row)*SKD + c] = (row < EPG) ? acc2 : 0.f;
}

// ---------------- la init: la[p][i][j] = dot(tq[i],tc[j]) / TEMP ----------------
__global__ void __launch_bounds__(256) k_lainit(const float* __restrict__ tall,
    float* __restrict__ la){
  __shared__ float tqs[256*32];
  __shared__ float tcs[256*32];
  int p = blockIdx.x, t = threadIdx.x;
  const float* tq = tall + (size_t)(2*p)*8192;
  const float* tc = tall + (size_t)(2*p+1)*8192;
  for (int i=t;i<8192;i+=256){ tqs[i]=tq[i]; tcs[i]=tc[i]; }
  __syncthreads();
  float creg[32];
  #pragma unroll
  for (int k=0;k<32;k++) creg[k]=tcs[t*32+k];  // thread owns column t
  float* out = la + (size_t)p*65536;
  for (int i=0;i<256;i++){
    float acc = 0.f;
    #pragma unroll
    for (int k=0;k<32;k+=4){
      const float4 q4 = *(const float4*)&tqs[i*32+k];
      acc = fmaf(q4.x,creg[k], fmaf(q4.y,creg[k+1], fmaf(q4.z,creg[k+2], fmaf(q4.w,creg[k+3], acc))));
    }
    out[(size_t)i*256 + t] = acc * 10.0f;   // / TEMP
  }
}

// ---------------- Sinkhorn: 20 iters, one block per pair ----------------
__global__ void __launch_bounds__(256) k_sinkhorn(float* __restrict__ la){
  float* A = la + (size_t)blockIdx.x*65536;
  int t = threadIdx.x;
  int wave = t>>6, lane = t&63;
  for (int it=0; it<20; it++){
    // row normalize (axis=2): one wave per row
    for (int rr=0; rr<64; rr++){
      int i = rr*4 + wave;
      float4 v = *(float4*)&A[(size_t)i*256 + lane*4];
      float m = fmaxf(fmaxf(v.x,v.y), fmaxf(v.z,v.w));
      #pragma unroll
      for (int off=32; off; off>>=1) m = fmaxf(m, __shfl_xor(m, off));
      float s = __expf(v.x-m)+__expf(v.y-m)+__expf(v.z-m)+__expf(v.w-m);
      #pragma unroll
      for (int off=32; off; off>>=1) s += __shfl_xor(s, off);
      float lse = m + __logf(s);
      v.x-=lse; v.y-=lse; v.z-=lse; v.w-=lse;
      *(float4*)&A[(size_t)i*256 + lane*4] = v;
    }
    __syncthreads();
    // col normalize (axis=1): thread owns column t, online LSE
    float m = -INFINITY, s = 0.f;
    for (int i=0;i<256;i++){
      float x = A[(size_t)i*256 + t];
      float mn = fmaxf(m, x);
      s = s*__expf(m-mn) + __expf(x-mn);
      m = mn;
    }
    float lse = m + __logf(s);
    for (int i=0;i<256;i++) A[(size_t)i*256 + t] -= lse;
    __syncthreads();
  }
}

// ---------------- loss: -sum relu(q - exp(la) @ c) ----------------
// grid = 256 pairs * 8 row-tiles (32 rows); 256 threads (thread = feature col)
__global__ void __launch_bounds__(256) k_loss(const float* __restrict__ la,
    const float* __restrict__ ef, float* __restrict__ out){
  __shared__ float ps[32][32];
  __shared__ float cs[32][256];
  __shared__ float red[4];
  int bid = blockIdx.x;
  int p = bid>>3, i0 = (bid&7)*32;
  int t = threadIdx.x;
  float acc[32];
  #pragma unroll
  for (int r=0;r<32;r++) acc[r]=0.f;
  const float* lap  = la + (size_t)p*65536;
  const float* crow = ef + (size_t)(2*p+1)*EPG*MSGD;
  for (int kt=0; kt<EPG; kt+=32){
    __syncthreads();
    for (int i=t;i<32*32;i+=256){
      int r = i>>5, k = i&31;
      ps[r][k] = (kt+k < EPG) ? __expf(lap[(size_t)(i0+r)*256 + kt+k]) : 0.f;
    }
    for (int i=t;i<32*256;i+=256){
      int k = i>>8, f = i&255;
      cs[k][f] = (kt+k < EPG) ? crow[(size_t)(kt+k)*MSGD + f] : 0.f;
    }
    __syncthreads();
    for (int k=0;k<32;k++){
      float cv = cs[k][t];
      #pragma unroll
      for (int r=0;r<32;r++) acc[r] = fmaf(ps[r][k], cv, acc[r]);
    }
  }
  const float* qrow = ef + (size_t)(2*p)*EPG*MSGD;
  float s = 0.f;
  #pragma unroll
  for (int r=0;r<32;r++){
    int row = i0+r;
    float q = (row < EPG) ? qrow[(size_t)row*MSGD + t] : 0.f;
    s += fmaxf(q - acc[r], 0.f);
  }
  #pragma unroll
  for (int off=32; off; off>>=1) s += __shfl_xor(s, off);
  if ((t&63)==0) red[t>>6]=s;
  __syncthreads();
  if (t==0) atomicAdd(&out[p], -(red[0]+red[1]+red[2]+red[3]));
}

// ---------------- launch ----------------
extern "C" void kernel_launch(void* const* d_in, const int* in_sizes, int n_in,
                              void* d_out, int out_size, void* d_ws, size_t ws_size,
                              hipStream_t stream){
  const float* nf   = (const float*)d_in[0];
  const float* ef   = (const float*)d_in[1];
  const int*   fidx = (const int*)d_in[2];
  const int*   tidx = (const int*)d_in[3];
  const float* enw  = (const float*)d_in[4];
  const float* enb  = (const float*)d_in[5];
  const float* eew  = (const float*)d_in[6];
  const float* eeb  = (const float*)d_in[7];
  const float* mw1  = (const float*)d_in[8];
  const float* mb1  = (const float*)d_in[9];
  const float* mw2  = (const float*)d_in[10];
  const float* mb2  = (const float*)d_in[11];
  const float* rw1  = (const float*)d_in[12];
  const float* rb1  = (const float*)d_in[13];
  const float* rw2  = (const float*)d_in[14];
  const float* rb2  = (const float*)d_in[15];
  const float* wih  = (const float*)d_in[16];
  const float* bih  = (const float*)d_in[17];
  const float* whh  = (const float*)d_in[18];
  const float* bhh  = (const float*)d_in[19];
  const float* skw1 = (const float*)d_in[20];
  const float* skb1 = (const float*)d_in[21];
  const float* skw2 = (const float*)d_in[22];
  const float* skb2 = (const float*)d_in[23];
  float* out = (float*)d_out;

  float* ws = (float*)d_ws;
  float* h_a    = ws;                              // 4,194,304
  float* h_b    = h_a + (size_t)NN*HD;             // 4,194,304
  float* e_enc  = h_b + (size_t)NN*HD;             // 6,553,600
  float* e_fin  = e_enc + (size_t)NE*EED;          // 26,214,400 (agg aliases head)
  float* agg    = e_fin;                           // 8,388,608 (loop phase only)
  float* t_all  = e_fin + (size_t)NE*MSGD;         // 4,194,304
  float* la     = t_all + (size_t)NG*256*SKD;      // 16,777,216

  k_enc_node<<<NN/2, 256, 0, stream>>>(nf, enw, enb, h_a);
  k_enc_edge<<<NE/4, 256, 0, stream>>>(ef, eew, eeb, e_enc);

  float* hc = h_a; float* hn = h_b;
  for (int step=0; step<5; step++){
    hipMemsetAsync(agg, 0, (size_t)NN*MSGD*sizeof(float), stream);
    k_msg<false><<<NE/16, 256, 0, stream>>>(hc, e_enc, fidx, tidx,
        mw1, mb1, mw2, mb2, rw1, rb1, rw2, rb2, agg);
    k_gru<<<NN/16, 384, 0, stream>>>(hc, agg, wih, bih, whh, bhh, hn);
    float* tmp = hc; hc = hn; hn = tmp;
  }
  // final messages -> e_final
  k_msg<true><<<NE/16, 256, 0, stream>>>(hc, e_enc, fidx, tidx,
      mw1, mb1, mw2, mb2, rw1, rb1, rw2, rb2, e_fin);

  k_tall<<<NG*32, 256, 0, stream>>>(e_fin, skw1, skb1, skw2, skb2, t_all);
  k_lainit<<<NP, 256, 0, stream>>>(t_all, la);
  k_sinkhorn<<<NP, 256, 0, stream>>>(la);

  hipMemsetAsync(out, 0, (size_t)NP*sizeof(float), stream);
  k_loss<<<NP*8, 256, 0, stream>>>(la, e_fin, out);
}

// Round 2
// 5366.060 us; speedup vs baseline: 3.5128x; 3.5128x over previous
//
#include <hip/hip_runtime.h>
#include <math.h>

typedef __attribute__((ext_vector_type(4))) float f32x4;
typedef __attribute__((ext_vector_type(8))) short s16x8;

#define NN 32768      // nodes
#define NE 102400     // edges
#define HD 128        // H
#define EED 64        // edge enc dim
#define MSGD 256
#define NG 512        // graphs
#define EPG 200       // edges per graph
#define NP 256        // pairs
#define SKD 32

__device__ inline short f2bf(float x){
  union{float f; unsigned u;} z; z.f=x;
  unsigned r = (z.u + 0x7fffu + ((z.u>>16)&1u)) >> 16;
  return (short)r;
}

// ---------------- node encoder: h = nf @ Wn + bn ----------------
__global__ void __launch_bounds__(256) k_enc_node(const float* __restrict__ nf,
    const float* __restrict__ W, const float* __restrict__ b, float* __restrict__ h){
  __shared__ float Ws[16*128];
  int t = threadIdx.x;
  for (int i=t;i<16*128;i+=256) Ws[i]=W[i];
  __syncthreads();
  int node = blockIdx.x*2 + (t>>7);
  int f = t & 127;
  const float* x = nf + node*16;
  float acc = b[f];
  #pragma unroll
  for (int k=0;k<16;k++) acc = fmaf(x[k], Ws[k*128+f], acc);
  h[node*HD+f] = acc;
}

// ---------------- edge encoder: e = ef @ We + be ----------------
__global__ void __launch_bounds__(256) k_enc_edge(const float* __restrict__ ef,
    const float* __restrict__ W, const float* __restrict__ b, float* __restrict__ ee){
  __shared__ float Ws[16*64];
  int t = threadIdx.x;
  for (int i=t;i<16*64;i+=256) Ws[i]=W[i];
  __syncthreads();
  int edge = blockIdx.x*4 + (t>>6);
  int f = t & 63;
  const float* x = ef + edge*16;
  float acc = b[f];
  #pragma unroll
  for (int k=0;k<16;k++) acc = fmaf(x[k], Ws[k*64+f], acc);
  ee[edge*EED+f] = acc;
}

// ---------------- weight pack: W[K][256] f32 -> bf16 MFMA B-frag order ----------------
// dst[((kt*16+nt)*64+l)*8+j] = bf16(W[kt*32 + (l>>4)*8 + j][nt*16 + (l&15)])
__global__ void __launch_bounds__(256) k_pack(const float* __restrict__ W,
    short* __restrict__ dst, int K){
  int i = blockIdx.x*256 + threadIdx.x;
  if (i >= (K/32)*16*64) return;
  int l = i & 63, tile = i >> 6;
  int nt = tile & 15, kt = tile >> 4;
  int lr = l & 15, lq = l >> 4;
  s16x8 v;
  #pragma unroll
  for (int j=0;j<8;j++)
    v[j] = f2bf(W[(size_t)(kt*32 + lq*8 + j)*256 + nt*16 + lr]);
  *((s16x8*)dst + i) = v;
}

// ---------------- message MLPs (fwd+rev), bf16 MFMA ----------------
// 64 edges/block, 4 waves; wave w owns output cols [w*64, w*64+64).
// X = [h_s | h_d | e] staged bf16 in LDS; rev dir = k-chunk permutation (kt^4).
template<bool FINAL>
__global__ void __launch_bounds__(256,2) k_msg(const float* __restrict__ h,
    const float* __restrict__ ee, const int* __restrict__ from_idx, const int* __restrict__ to_idx,
    const short* __restrict__ w1f, const float* __restrict__ b1f,
    const short* __restrict__ w2f, const float* __restrict__ b2f,
    const short* __restrict__ w1r, const float* __restrict__ b1r,
    const short* __restrict__ w2r, const float* __restrict__ b2r,
    float* __restrict__ outp){
  __shared__ __align__(16) short Xs[64][328];   // 41984 B, stride 328 -> 2-way bank alias (free)
  __shared__ __align__(16) short Ys[64][264];   // 33792 B
  __shared__ int sidx[64], didx[64];
  int t = threadIdx.x;
  int e0 = blockIdx.x*64;
  if (t < 64){ sidx[t]=from_idx[e0+t]; didx[t]=to_idx[e0+t]; }
  __syncthreads();
  // stage X as bf16: 64 rows x 320 cols, 8 f32 -> 8 bf16 per chunk
  for (int i=t; i<64*40; i+=256){
    int r = i/40, c8 = (i - r*40)*8;
    const float* src; int off;
    if (c8 < 128){ src = h + (size_t)sidx[r]*HD; off = c8; }
    else if (c8 < 256){ src = h + (size_t)didx[r]*HD; off = c8-128; }
    else { src = ee + (size_t)(e0+r)*EED; off = c8-256; }
    float4 a = *(const float4*)(src+off);
    float4 b = *(const float4*)(src+off+4);
    s16x8 v;
    v[0]=f2bf(a.x); v[1]=f2bf(a.y); v[2]=f2bf(a.z); v[3]=f2bf(a.w);
    v[4]=f2bf(b.x); v[5]=f2bf(b.y); v[6]=f2bf(b.z); v[7]=f2bf(b.w);
    *(s16x8*)&Xs[r][c8] = v;
  }
  __syncthreads();

  int wv = t>>6, l = t&63, lr = l&15, lq = l>>4;
  int cbase = wv*64;

  f32x4 fsv[4][4];

  for (int dir=0; dir<2; dir++){
    const s16x8* W1v = (const s16x8*)(dir ? w1r : w1f);
    const float* B1  = dir ? b1r : b1f;
    const s16x8* W2v = (const s16x8*)(dir ? w2r : w2f);
    const float* B2  = dir ? b2r : b2f;

    f32x4 acc[4][4];
    #pragma unroll
    for (int ct=0; ct<4; ct++){
      float bb = B1[cbase + ct*16 + lr];
      #pragma unroll
      for (int rt=0; rt<4; rt++) acc[rt][ct] = (f32x4){bb,bb,bb,bb};
    }
    // layer 1: K=320, 10 k-steps of 32
    for (int kt=0; kt<10; kt++){
      int sc = (dir && kt<8) ? (kt^4) : kt;   // rev: swap h_s/h_d 128-blocks
      s16x8 af[4], bfr[4];
      #pragma unroll
      for (int rt=0; rt<4; rt++) af[rt] = *(const s16x8*)&Xs[rt*16+lr][sc*32 + lq*8];
      #pragma unroll
      for (int ct=0; ct<4; ct++) bfr[ct] = W1v[(size_t)(kt*16 + wv*4 + ct)*64 + l];
      #pragma unroll
      for (int rt=0; rt<4; rt++)
        #pragma unroll
        for (int ct=0; ct<4; ct++)
          acc[rt][ct] = __builtin_amdgcn_mfma_f32_16x16x32_bf16(af[rt], bfr[ct], acc[rt][ct], 0,0,0);
    }
    // relu -> bf16 -> Ys   (C/D layout: row=(l>>4)*4+r, col=l&15)
    #pragma unroll
    for (int rt=0; rt<4; rt++)
      #pragma unroll
      for (int ct=0; ct<4; ct++)
        #pragma unroll
        for (int r=0; r<4; r++)
          Ys[rt*16 + lq*4 + r][cbase + ct*16 + lr] = f2bf(fmaxf(acc[rt][ct][r], 0.f));
    __syncthreads();

    f32x4 acc2[4][4];
    #pragma unroll
    for (int ct=0; ct<4; ct++){
      float bb = B2[cbase + ct*16 + lr];
      #pragma unroll
      for (int rt=0; rt<4; rt++) acc2[rt][ct] = (f32x4){bb,bb,bb,bb};
    }
    // layer 2: K=256, 8 k-steps
    for (int kt=0; kt<8; kt++){
      s16x8 af[4], bfr[4];
      #pragma unroll
      for (int rt=0; rt<4; rt++) af[rt] = *(const s16x8*)&Ys[rt*16+lr][kt*32 + lq*8];
      #pragma unroll
      for (int ct=0; ct<4; ct++) bfr[ct] = W2v[(size_t)(kt*16 + wv*4 + ct)*64 + l];
      #pragma unroll
      for (int rt=0; rt<4; rt++)
        #pragma unroll
        for (int ct=0; ct<4; ct++)
          acc2[rt][ct] = __builtin_amdgcn_mfma_f32_16x16x32_bf16(af[rt], bfr[ct], acc2[rt][ct], 0,0,0);
    }

    if (FINAL){
      if (dir==0){
        #pragma unroll
        for (int rt=0; rt<4; rt++)
          #pragma unroll
          for (int ct=0; ct<4; ct++) fsv[rt][ct] = acc2[rt][ct];
      } else {
        #pragma unroll
        for (int rt=0; rt<4; rt++)
          #pragma unroll
          for (int ct=0; ct<4; ct++)
            #pragma unroll
            for (int r=0; r<4; r++){
              int row = e0 + rt*16 + lq*4 + r;
              outp[(size_t)row*MSGD + cbase + ct*16 + lr] = fsv[rt][ct][r] + acc2[rt][ct][r];
            }
      }
    } else {
      const int* gidx = dir ? sidx : didx;
      #pragma unroll
      for (int rt=0; rt<4; rt++)
        #pragma unroll
        for (int ct=0; ct<4; ct++)
          #pragma unroll
          for (int r=0; r<4; r++){
            int row = rt*16 + lq*4 + r;
            atomicAdd(&outp[(size_t)gidx[row]*MSGD + cbase + ct*16 + lr], acc2[rt][ct][r]);
          }
    }
    __syncthreads();   // Ys (and fsv ordering) safe before next dir
  }
}

// ---------------- GRU: gi=agg@Wih+bih, gh=h@Whh+bhh, gate update ----------------
__global__ void __launch_bounds__(384,3) k_gru(const float* __restrict__ h,
    const float* __restrict__ agg,
    const float* __restrict__ Wih, const float* __restrict__ bih,
    const float* __restrict__ Whh, const float* __restrict__ bhh,
    float* __restrict__ hnew){
  __shared__ float as[16][256];
  __shared__ float hs[16][128];
  __shared__ float gis[16][384];
  __shared__ float ghs[16][384];
  int t = threadIdx.x;
  int n0 = blockIdx.x*16;
  for (int i=t;i<16*256;i+=384) as[0][i]=agg[(size_t)n0*256 + i];
  for (int i=t;i<16*128;i+=384) hs[0][i]=h[(size_t)n0*128 + i];
  __syncthreads();
  float gi[16], gh[16];
  {
    float bi=bih[t], bh=bhh[t];
    #pragma unroll
    for (int n=0;n<16;n++){ gi[n]=bi; gh[n]=bh; }
  }
  for (int k=0;k<256;k+=4){
    float w0=Wih[(k+0)*384+t], w1=Wih[(k+1)*384+t], w2=Wih[(k+2)*384+t], w3=Wih[(k+3)*384+t];
    #pragma unroll
    for (int n=0;n<16;n++){
      const float4 a4 = *(const float4*)&as[n][k];
      gi[n] = fmaf(a4.x,w0, fmaf(a4.y,w1, fmaf(a4.z,w2, fmaf(a4.w,w3, gi[n]))));
    }
  }
  for (int k=0;k<128;k+=4){
    float w0=Whh[(k+0)*384+t], w1=Whh[(k+1)*384+t], w2=Whh[(k+2)*384+t], w3=Whh[(k+3)*384+t];
    #pragma unroll
    for (int n=0;n<16;n++){
      const float4 h4 = *(const float4*)&hs[n][k];
      gh[n] = fmaf(h4.x,w0, fmaf(h4.y,w1, fmaf(h4.z,w2, fmaf(h4.w,w3, gh[n]))));
    }
  }
  #pragma unroll
  for (int n=0;n<16;n++){ gis[n][t]=gi[n]; ghs[n][t]=gh[n]; }
  __syncthreads();
  for (int i=t;i<16*128;i+=384){
    int n = i>>7, f = i&127;
    float r = 1.f/(1.f + __expf(-(gis[n][f]      + ghs[n][f])));
    float z = 1.f/(1.f + __expf(-(gis[n][128+f]  + ghs[n][128+f])));
    float nn = tanhf(gis[n][256+f] + r*ghs[n][256+f]);
    hnew[(size_t)(n0+n)*128 + f] = (1.f - z)*nn + z*hs[n][f];
  }
}

// ---------------- SK transform ----------------
__global__ void __launch_bounds__(256) k_tall(const float* __restrict__ ef,
    const float* __restrict__ W1, const float* __restrict__ b1,
    const float* __restrict__ W2, const float* __restrict__ b2,
    float* __restrict__ tall){
  __shared__ float W1s[256*32];
  __shared__ float W2s[32*32];
  __shared__ float b1s[32], b2s[32];
  __shared__ float xsr[8][256];
  __shared__ float y1s[8][32];
  int t = threadIdx.x;
  for (int i=t;i<256*32;i+=256) W1s[i]=W1[i];
  for (int i=t;i<32*32;i+=256)  W2s[i]=W2[i];
  if (t<32){ b1s[t]=b1[t]; b2s[t]=b2[t]; }
  int g = blockIdx.x >> 5;
  int i0 = (blockIdx.x & 31)*8;
  for (int i=t;i<8*256;i+=256){
    int r = i>>8, k = i&255;
    int row = i0+r;
    xsr[r][k] = (row < EPG) ? ef[((size_t)g*EPG + row)*MSGD + k] : 0.f;
  }
  __syncthreads();
  int r = t>>5, c = t&31;
  float acc = b1s[c];
  for (int k=0;k<256;k+=4){
    const float4 x4 = *(const float4*)&xsr[r][k];
    acc = fmaf(x4.x,W1s[(k+0)*32+c], fmaf(x4.y,W1s[(k+1)*32+c],
          fmaf(x4.z,W1s[(k+2)*32+c], fmaf(x4.w,W1s[(k+3)*32+c], acc))));
  }
  y1s[r][c] = fmaxf(acc, 0.f);
  __syncthreads();
  float acc2 = b2s[c];
  #pragma unroll
  for (int k=0;k<32;k++) acc2 = fmaf(y1s[r][k], W2s[k*32+c], acc2);
  int row = i0+r;
  tall[((size_t)g*256 + row)*SKD + c] = (row < EPG) ? acc2 : 0.f;
}

// ---------------- la init ----------------
__global__ void __launch_bounds__(256) k_lainit(const float* __restrict__ tall,
    float* __restrict__ la){
  __shared__ float tqs[256*32];
  __shared__ float tcs[256*32];
  int p = blockIdx.x, t = threadIdx.x;
  const float* tq = tall + (size_t)(2*p)*8192;
  const float* tc = tall + (size_t)(2*p+1)*8192;
  for (int i=t;i<8192;i+=256){ tqs[i]=tq[i]; tcs[i]=tc[i]; }
  __syncthreads();
  float creg[32];
  #pragma unroll
  for (int k=0;k<32;k++) creg[k]=tcs[t*32+k];
  float* out = la + (size_t)p*65536;
  for (int i=0;i<256;i++){
    float acc = 0.f;
    #pragma unroll
    for (int k=0;k<32;k+=4){
      const float4 q4 = *(const float4*)&tqs[i*32+k];
      acc = fmaf(q4.x,creg[k], fmaf(q4.y,creg[k+1], fmaf(q4.z,creg[k+2], fmaf(q4.w,creg[k+3], acc))));
    }
    out[(size_t)i*256 + t] = acc * 10.0f;
  }
}

// ---------------- Sinkhorn ----------------
__global__ void __launch_bounds__(256) k_sinkhorn(float* __restrict__ la){
  float* A = la + (size_t)blockIdx.x*65536;
  int t = threadIdx.x;
  int wave = t>>6, lane = t&63;
  for (int it=0; it<20; it++){
    for (int rr=0; rr<64; rr++){
      int i = rr*4 + wave;
      float4 v = *(float4*)&A[(size_t)i*256 + lane*4];
      float m = fmaxf(fmaxf(v.x,v.y), fmaxf(v.z,v.w));
      #pragma unroll
      for (int off=32; off; off>>=1) m = fmaxf(m, __shfl_xor(m, off));
      float s = __expf(v.x-m)+__expf(v.y-m)+__expf(v.z-m)+__expf(v.w-m);
      #pragma unroll
      for (int off=32; off; off>>=1) s += __shfl_xor(s, off);
      float lse = m + __logf(s);
      v.x-=lse; v.y-=lse; v.z-=lse; v.w-=lse;
      *(float4*)&A[(size_t)i*256 + lane*4] = v;
    }
    __syncthreads();
    float m = -INFINITY, s = 0.f;
    for (int i=0;i<256;i++){
      float x = A[(size_t)i*256 + t];
      float mn = fmaxf(m, x);
      s = s*__expf(m-mn) + __expf(x-mn);
      m = mn;
    }
    float lse = m + __logf(s);
    for (int i=0;i<256;i++) A[(size_t)i*256 + t] -= lse;
    __syncthreads();
  }
}

// ---------------- loss ----------------
__global__ void __launch_bounds__(256) k_loss(const float* __restrict__ la,
    const float* __restrict__ ef, float* __restrict__ out){
  __shared__ float ps[32][32];
  __shared__ float cs[32][256];
  __shared__ float red[4];
  int bid = blockIdx.x;
  int p = bid>>3, i0 = (bid&7)*32;
  int t = threadIdx.x;
  float acc[32];
  #pragma unroll
  for (int r=0;r<32;r++) acc[r]=0.f;
  const float* lap  = la + (size_t)p*65536;
  const float* crow = ef + (size_t)(2*p+1)*EPG*MSGD;
  for (int kt=0; kt<EPG; kt+=32){
    __syncthreads();
    for (int i=t;i<32*32;i+=256){
      int r = i>>5, k = i&31;
      ps[r][k] = (kt+k < EPG) ? __expf(lap[(size_t)(i0+r)*256 + kt+k]) : 0.f;
    }
    for (int i=t;i<32*256;i+=256){
      int k = i>>8, f = i&255;
      cs[k][f] = (kt+k < EPG) ? crow[(size_t)(kt+k)*MSGD + f] : 0.f;
    }
    __syncthreads();
    for (int k=0;k<32;k++){
      float cv = cs[k][t];
      #pragma unroll
      for (int r=0;r<32;r++) acc[r] = fmaf(ps[r][k], cv, acc[r]);
    }
  }
  const float* qrow = ef + (size_t)(2*p)*EPG*MSGD;
  float s = 0.f;
  #pragma unroll
  for (int r=0;r<32;r++){
    int row = i0+r;
    float q = (row < EPG) ? qrow[(size_t)row*MSGD + t] : 0.f;
    s += fmaxf(q - acc[r], 0.f);
  }
  #pragma unroll
  for (int off=32; off; off>>=1) s += __shfl_xor(s, off);
  if ((t&63)==0) red[t>>6]=s;
  __syncthreads();
  if (t==0) atomicAdd(&out[p], -(red[0]+red[1]+red[2]+red[3]));
}

// ---------------- launch ----------------
extern "C" void kernel_launch(void* const* d_in, const int* in_sizes, int n_in,
                              void* d_out, int out_size, void* d_ws, size_t ws_size,
                              hipStream_t stream){
  const float* nf   = (const float*)d_in[0];
  const float* ef   = (const float*)d_in[1];
  const int*   fidx = (const int*)d_in[2];
  const int*   tidx = (const int*)d_in[3];
  const float* enw  = (const float*)d_in[4];
  const float* enb  = (const float*)d_in[5];
  const float* eew  = (const float*)d_in[6];
  const float* eeb  = (const float*)d_in[7];
  const float* mw1  = (const float*)d_in[8];
  const float* mb1  = (const float*)d_in[9];
  const float* mw2  = (const float*)d_in[10];
  const float* mb2  = (const float*)d_in[11];
  const float* rw1  = (const float*)d_in[12];
  const float* rb1  = (const float*)d_in[13];
  const float* rw2  = (const float*)d_in[14];
  const float* rb2  = (const float*)d_in[15];
  const float* wih  = (const float*)d_in[16];
  const float* bih  = (const float*)d_in[17];
  const float* whh  = (const float*)d_in[18];
  const float* bhh  = (const float*)d_in[19];
  const float* skw1 = (const float*)d_in[20];
  const float* skb1 = (const float*)d_in[21];
  const float* skw2 = (const float*)d_in[22];
  const float* skb2 = (const float*)d_in[23];
  float* out = (float*)d_out;

  float* ws = (float*)d_ws;
  float* h_a    = ws;
  float* h_b    = h_a + (size_t)NN*HD;
  float* e_enc  = h_b + (size_t)NN*HD;
  float* e_fin  = e_enc + (size_t)NE*EED;
  float* agg    = e_fin;                           // aliases e_fin (loop phase only)
  float* t_all  = e_fin + (size_t)NE*MSGD;
  float* la     = t_all + (size_t)NG*256*SKD;

  // packed bf16 weights alias la (la written only after all k_msg are done)
  short* w1f_p = (short*)la;
  short* w1r_p = w1f_p + 320*256;
  short* w2f_p = w1r_p + 320*256;
  short* w2r_p = w2f_p + 256*256;

  k_pack<<<40, 256, 0, stream>>>(mw1, w1f_p, 320);
  k_pack<<<40, 256, 0, stream>>>(rw1, w1r_p, 320);
  k_pack<<<32, 256, 0, stream>>>(mw2, w2f_p, 256);
  k_pack<<<32, 256, 0, stream>>>(rw2, w2r_p, 256);

  k_enc_node<<<NN/2, 256, 0, stream>>>(nf, enw, enb, h_a);
  k_enc_edge<<<NE/4, 256, 0, stream>>>(ef, eew, eeb, e_enc);

  float* hc = h_a; float* hn = h_b;
  for (int step=0; step<5; step++){
    hipMemsetAsync(agg, 0, (size_t)NN*MSGD*sizeof(float), stream);
    k_msg<false><<<NE/64, 256, 0, stream>>>(hc, e_enc, fidx, tidx,
        w1f_p, mb1, w2f_p, mb2, w1r_p, rb1, w2r_p, rb2, agg);
    k_gru<<<NN/16, 384, 0, stream>>>(hc, agg, wih, bih, whh, bhh, hn);
    float* tmp = hc; hc = hn; hn = tmp;
  }
  k_msg<true><<<NE/64, 256, 0, stream>>>(hc, e_enc, fidx, tidx,
      w1f_p, mb1, w2f_p, mb2, w1r_p, rb1, w2r_p, rb2, e_fin);

  k_tall<<<NG*32, 256, 0, stream>>>(e_fin, skw1, skb1, skw2, skb2, t_all);
  k_lainit<<<NP, 256, 0, stream>>>(t_all, la);
  k_sinkhorn<<<NP, 256, 0, stream>>>(la);

  hipMemsetAsync(out, 0, (size_t)NP*sizeof(float), stream);
  k_loss<<<NP*8, 256, 0, stream>>>(la, e_fin, out);
}

// Round 3
// 3690.021 us; speedup vs baseline: 5.1083x; 1.4542x over previous
//
#include <hip/hip_runtime.h>
#include <math.h>

typedef __attribute__((ext_vector_type(4))) float f32x4;
typedef __attribute__((ext_vector_type(8))) short s16x8;

#define NN 32768      // nodes
#define NE 102400     // edges
#define HD 128        // H
#define EED 64        // edge enc dim
#define MSGD 256
#define NG 512        // graphs
#define EPG 200       // edges per graph
#define NP 256        // pairs
#define SKD 32

__device__ inline short f2bf(float x){
  union{float f; unsigned u;} z; z.f=x;
  unsigned r = (z.u + 0x7fffu + ((z.u>>16)&1u)) >> 16;
  return (short)r;
}

// ---------------- node encoder: h = nf @ Wn + bn ----------------
__global__ void __launch_bounds__(256) k_enc_node(const float* __restrict__ nf,
    const float* __restrict__ W, const float* __restrict__ b, float* __restrict__ h){
  __shared__ float Ws[16*128];
  int t = threadIdx.x;
  for (int i=t;i<16*128;i+=256) Ws[i]=W[i];
  __syncthreads();
  int node = blockIdx.x*2 + (t>>7);
  int f = t & 127;
  const float* x = nf + node*16;
  float acc = b[f];
  #pragma unroll
  for (int k=0;k<16;k++) acc = fmaf(x[k], Ws[k*128+f], acc);
  h[node*HD+f] = acc;
}

// ---------------- edge encoder: e = ef @ We + be ----------------
__global__ void __launch_bounds__(256) k_enc_edge(const float* __restrict__ ef,
    const float* __restrict__ W, const float* __restrict__ b, float* __restrict__ ee){
  __shared__ float Ws[16*64];
  int t = threadIdx.x;
  for (int i=t;i<16*64;i+=256) Ws[i]=W[i];
  __syncthreads();
  int edge = blockIdx.x*4 + (t>>6);
  int f = t & 63;
  const float* x = ef + edge*16;
  float acc = b[f];
  #pragma unroll
  for (int k=0;k<16;k++) acc = fmaf(x[k], Ws[k*64+f], acc);
  ee[edge*EED+f] = acc;
}

// ---------------- weight pack: W[K][256] f32 -> bf16 MFMA B-frag order ----------------
__global__ void __launch_bounds__(256) k_pack(const float* __restrict__ W,
    short* __restrict__ dst, int K){
  int i = blockIdx.x*256 + threadIdx.x;
  if (i >= (K/32)*16*64) return;
  int l = i & 63, tile = i >> 6;
  int nt = tile & 15, kt = tile >> 4;
  int lr = l & 15, lq = l >> 4;
  s16x8 v;
  #pragma unroll
  for (int j=0;j<8;j++)
    v[j] = f2bf(W[(size_t)(kt*32 + lq*8 + j)*256 + nt*16 + lr]);
  *((s16x8*)dst + i) = v;
}

// ---------------- message MLPs (fwd+rev), bf16 MFMA ----------------
template<bool FINAL>
__global__ void __launch_bounds__(256,2) k_msg(const float* __restrict__ h,
    const float* __restrict__ ee, const int* __restrict__ from_idx, const int* __restrict__ to_idx,
    const short* __restrict__ w1f, const float* __restrict__ b1f,
    const short* __restrict__ w2f, const float* __restrict__ b2f,
    const short* __restrict__ w1r, const float* __restrict__ b1r,
    const short* __restrict__ w2r, const float* __restrict__ b2r,
    float* __restrict__ outp){
  __shared__ __align__(16) short Xs[64][328];
  __shared__ __align__(16) short Ys[64][264];
  __shared__ int sidx[64], didx[64];
  int t = threadIdx.x;
  int e0 = blockIdx.x*64;
  if (t < 64){ sidx[t]=from_idx[e0+t]; didx[t]=to_idx[e0+t]; }
  __syncthreads();
  for (int i=t; i<64*40; i+=256){
    int r = i/40, c8 = (i - r*40)*8;
    const float* src; int off;
    if (c8 < 128){ src = h + (size_t)sidx[r]*HD; off = c8; }
    else if (c8 < 256){ src = h + (size_t)didx[r]*HD; off = c8-128; }
    else { src = ee + (size_t)(e0+r)*EED; off = c8-256; }
    float4 a = *(const float4*)(src+off);
    float4 b = *(const float4*)(src+off+4);
    s16x8 v;
    v[0]=f2bf(a.x); v[1]=f2bf(a.y); v[2]=f2bf(a.z); v[3]=f2bf(a.w);
    v[4]=f2bf(b.x); v[5]=f2bf(b.y); v[6]=f2bf(b.z); v[7]=f2bf(b.w);
    *(s16x8*)&Xs[r][c8] = v;
  }
  __syncthreads();

  int wv = t>>6, l = t&63, lr = l&15, lq = l>>4;
  int cbase = wv*64;

  f32x4 fsv[4][4];

  for (int dir=0; dir<2; dir++){
    const s16x8* W1v = (const s16x8*)(dir ? w1r : w1f);
    const float* B1  = dir ? b1r : b1f;
    const s16x8* W2v = (const s16x8*)(dir ? w2r : w2f);
    const float* B2  = dir ? b2r : b2f;

    f32x4 acc[4][4];
    #pragma unroll
    for (int ct=0; ct<4; ct++){
      float bb = B1[cbase + ct*16 + lr];
      #pragma unroll
      for (int rt=0; rt<4; rt++) acc[rt][ct] = (f32x4){bb,bb,bb,bb};
    }
    for (int kt=0; kt<10; kt++){
      int sc = (dir && kt<8) ? (kt^4) : kt;
      s16x8 af[4], bfr[4];
      #pragma unroll
      for (int rt=0; rt<4; rt++) af[rt] = *(const s16x8*)&Xs[rt*16+lr][sc*32 + lq*8];
      #pragma unroll
      for (int ct=0; ct<4; ct++) bfr[ct] = W1v[(size_t)(kt*16 + wv*4 + ct)*64 + l];
      #pragma unroll
      for (int rt=0; rt<4; rt++)
        #pragma unroll
        for (int ct=0; ct<4; ct++)
          acc[rt][ct] = __builtin_amdgcn_mfma_f32_16x16x32_bf16(af[rt], bfr[ct], acc[rt][ct], 0,0,0);
    }
    #pragma unroll
    for (int rt=0; rt<4; rt++)
      #pragma unroll
      for (int ct=0; ct<4; ct++)
        #pragma unroll
        for (int r=0; r<4; r++)
          Ys[rt*16 + lq*4 + r][cbase + ct*16 + lr] = f2bf(fmaxf(acc[rt][ct][r], 0.f));
    __syncthreads();

    f32x4 acc2[4][4];
    #pragma unroll
    for (int ct=0; ct<4; ct++){
      float bb = B2[cbase + ct*16 + lr];
      #pragma unroll
      for (int rt=0; rt<4; rt++) acc2[rt][ct] = (f32x4){bb,bb,bb,bb};
    }
    for (int kt=0; kt<8; kt++){
      s16x8 af[4], bfr[4];
      #pragma unroll
      for (int rt=0; rt<4; rt++) af[rt] = *(const s16x8*)&Ys[rt*16+lr][kt*32 + lq*8];
      #pragma unroll
      for (int ct=0; ct<4; ct++) bfr[ct] = W2v[(size_t)(kt*16 + wv*4 + ct)*64 + l];
      #pragma unroll
      for (int rt=0; rt<4; rt++)
        #pragma unroll
        for (int ct=0; ct<4; ct++)
          acc2[rt][ct] = __builtin_amdgcn_mfma_f32_16x16x32_bf16(af[rt], bfr[ct], acc2[rt][ct], 0,0,0);
    }

    if (FINAL){
      if (dir==0){
        #pragma unroll
        for (int rt=0; rt<4; rt++)
          #pragma unroll
          for (int ct=0; ct<4; ct++) fsv[rt][ct] = acc2[rt][ct];
      } else {
        #pragma unroll
        for (int rt=0; rt<4; rt++)
          #pragma unroll
          for (int ct=0; ct<4; ct++)
            #pragma unroll
            for (int r=0; r<4; r++){
              int row = e0 + rt*16 + lq*4 + r;
              outp[(size_t)row*MSGD + cbase + ct*16 + lr] = fsv[rt][ct][r] + acc2[rt][ct][r];
            }
      }
    } else {
      const int* gidx = dir ? sidx : didx;
      #pragma unroll
      for (int rt=0; rt<4; rt++)
        #pragma unroll
        for (int ct=0; ct<4; ct++)
          #pragma unroll
          for (int r=0; r<4; r++){
            int row = rt*16 + lq*4 + r;
            atomicAdd(&outp[(size_t)gidx[row]*MSGD + cbase + ct*16 + lr], acc2[rt][ct][r]);
          }
    }
    __syncthreads();
  }
}

// ---------------- GRU ----------------
__global__ void __launch_bounds__(384,3) k_gru(const float* __restrict__ h,
    const float* __restrict__ agg,
    const float* __restrict__ Wih, const float* __restrict__ bih,
    const float* __restrict__ Whh, const float* __restrict__ bhh,
    float* __restrict__ hnew){
  __shared__ float as[16][256];
  __shared__ float hs[16][128];
  __shared__ float gis[16][384];
  __shared__ float ghs[16][384];
  int t = threadIdx.x;
  int n0 = blockIdx.x*16;
  for (int i=t;i<16*256;i+=384) as[0][i]=agg[(size_t)n0*256 + i];
  for (int i=t;i<16*128;i+=384) hs[0][i]=h[(size_t)n0*128 + i];
  __syncthreads();
  float gi[16], gh[16];
  {
    float bi=bih[t], bh=bhh[t];
    #pragma unroll
    for (int n=0;n<16;n++){ gi[n]=bi; gh[n]=bh; }
  }
  for (int k=0;k<256;k+=4){
    float w0=Wih[(k+0)*384+t], w1=Wih[(k+1)*384+t], w2=Wih[(k+2)*384+t], w3=Wih[(k+3)*384+t];
    #pragma unroll
    for (int n=0;n<16;n++){
      const float4 a4 = *(const float4*)&as[n][k];
      gi[n] = fmaf(a4.x,w0, fmaf(a4.y,w1, fmaf(a4.z,w2, fmaf(a4.w,w3, gi[n]))));
    }
  }
  for (int k=0;k<128;k+=4){
    float w0=Whh[(k+0)*384+t], w1=Whh[(k+1)*384+t], w2=Whh[(k+2)*384+t], w3=Whh[(k+3)*384+t];
    #pragma unroll
    for (int n=0;n<16;n++){
      const float4 h4 = *(const float4*)&hs[n][k];
      gh[n] = fmaf(h4.x,w0, fmaf(h4.y,w1, fmaf(h4.z,w2, fmaf(h4.w,w3, gh[n]))));
    }
  }
  #pragma unroll
  for (int n=0;n<16;n++){ gis[n][t]=gi[n]; ghs[n][t]=gh[n]; }
  __syncthreads();
  for (int i=t;i<16*128;i+=384){
    int n = i>>7, f = i&127;
    float r = 1.f/(1.f + __expf(-(gis[n][f]      + ghs[n][f])));
    float z = 1.f/(1.f + __expf(-(gis[n][128+f]  + ghs[n][128+f])));
    float nn = tanhf(gis[n][256+f] + r*ghs[n][256+f]);
    hnew[(size_t)(n0+n)*128 + f] = (1.f - z)*nn + z*hs[n][f];
  }
}

// ---------------- SK transform ----------------
__global__ void __launch_bounds__(256) k_tall(const float* __restrict__ ef,
    const float* __restrict__ W1, const float* __restrict__ b1,
    const float* __restrict__ W2, const float* __restrict__ b2,
    float* __restrict__ tall){
  __shared__ float W1s[256*32];
  __shared__ float W2s[32*32];
  __shared__ float b1s[32], b2s[32];
  __shared__ float xsr[8][256];
  __shared__ float y1s[8][32];
  int t = threadIdx.x;
  for (int i=t;i<256*32;i+=256) W1s[i]=W1[i];
  for (int i=t;i<32*32;i+=256)  W2s[i]=W2[i];
  if (t<32){ b1s[t]=b1[t]; b2s[t]=b2[t]; }
  int g = blockIdx.x >> 5;
  int i0 = (blockIdx.x & 31)*8;
  for (int i=t;i<8*256;i+=256){
    int r = i>>8, k = i&255;
    int row = i0+r;
    xsr[r][k] = (row < EPG) ? ef[((size_t)g*EPG + row)*MSGD + k] : 0.f;
  }
  __syncthreads();
  int r = t>>5, c = t&31;
  float acc = b1s[c];
  for (int k=0;k<256;k+=4){
    const float4 x4 = *(const float4*)&xsr[r][k];
    acc = fmaf(x4.x,W1s[(k+0)*32+c], fmaf(x4.y,W1s[(k+1)*32+c],
          fmaf(x4.z,W1s[(k+2)*32+c], fmaf(x4.w,W1s[(k+3)*32+c], acc))));
  }
  y1s[r][c] = fmaxf(acc, 0.f);
  __syncthreads();
  float acc2 = b2s[c];
  #pragma unroll
  for (int k=0;k<32;k++) acc2 = fmaf(y1s[r][k], W2s[k*32+c], acc2);
  int row = i0+r;
  tall[((size_t)g*256 + row)*SKD + c] = (row < EPG) ? acc2 : 0.f;
}

// ---------------- la init ----------------
__global__ void __launch_bounds__(256) k_lainit(const float* __restrict__ tall,
    float* __restrict__ la){
  __shared__ float tqs[256*32];
  __shared__ float tcs[256*32];
  int p = blockIdx.x, t = threadIdx.x;
  const float* tq = tall + (size_t)(2*p)*8192;
  const float* tc = tall + (size_t)(2*p+1)*8192;
  for (int i=t;i<8192;i+=256){ tqs[i]=tq[i]; tcs[i]=tc[i]; }
  __syncthreads();
  float creg[32];
  #pragma unroll
  for (int k=0;k<32;k++) creg[k]=tcs[t*32+k];
  float* out = la + (size_t)p*65536;
  for (int i=0;i<256;i++){
    float acc = 0.f;
    #pragma unroll
    for (int k=0;k<32;k+=4){
      const float4 q4 = *(const float4*)&tqs[i*32+k];
      acc = fmaf(q4.x,creg[k], fmaf(q4.y,creg[k+1], fmaf(q4.z,creg[k+2], fmaf(q4.w,creg[k+3], acc))));
    }
    out[(size_t)i*256 + t] = acc * 10.0f;
  }
}

// ---------------- Sinkhorn: register-resident, r/c reformulation ----------------
// 1024 threads (16 waves); wave w owns rows w*16..w*16+15; lane l owns cols 4l..4l+3.
// A fixed in VGPRs (16 x float4); r_i = LSE_j(A-c), c_j = LSE_i(A-r).
// Writes plan = exp(A - r - c) in place.
__global__ void __launch_bounds__(1024) k_sinkhorn(float* __restrict__ la){
  __shared__ float cv[256];
  __shared__ float rv[256];
  __shared__ float pm[16][256];
  __shared__ float psm[16][256];
  int t = threadIdx.x;
  int w = t>>6, l = t&63;
  int rbase = w*16;
  float* A = la + (size_t)blockIdx.x*65536;
  float4 Areg[16];
  #pragma unroll
  for (int k=0;k<16;k++)
    Areg[k] = *(const float4*)&A[(size_t)(rbase+k)*256 + 4*l];
  if (t < 256) cv[t] = 0.f;
  __syncthreads();

  for (int it=0; it<20; it++){
    float4 c4 = *(const float4*)&cv[4*l];
    // ---- row pass: r_i = LSE_j(A[i,j]-c_j); row fully inside one wave ----
    #pragma unroll
    for (int k=0;k<16;k++){
      float4 v;
      v.x = Areg[k].x - c4.x; v.y = Areg[k].y - c4.y;
      v.z = Areg[k].z - c4.z; v.w = Areg[k].w - c4.w;
      float m = fmaxf(fmaxf(v.x,v.y), fmaxf(v.z,v.w));
      #pragma unroll
      for (int off=32; off; off>>=1) m = fmaxf(m, __shfl_xor(m, off));
      float s = __expf(v.x-m)+__expf(v.y-m)+__expf(v.z-m)+__expf(v.w-m);
      #pragma unroll
      for (int off=32; off; off>>=1) s += __shfl_xor(s, off);
      if (l==0) rv[rbase+k] = m + __logf(s);
    }
    // ---- col pass partials (reads rv of own wave only: no barrier needed) ----
    float4 mx = {-INFINITY,-INFINITY,-INFINITY,-INFINITY};
    #pragma unroll
    for (int k=0;k<16;k++){
      float rk = rv[rbase+k];
      mx.x = fmaxf(mx.x, Areg[k].x - rk);
      mx.y = fmaxf(mx.y, Areg[k].y - rk);
      mx.z = fmaxf(mx.z, Areg[k].z - rk);
      mx.w = fmaxf(mx.w, Areg[k].w - rk);
    }
    float4 sm = {0.f,0.f,0.f,0.f};
    #pragma unroll
    for (int k=0;k<16;k++){
      float rk = rv[rbase+k];
      sm.x += __expf(Areg[k].x - rk - mx.x);
      sm.y += __expf(Areg[k].y - rk - mx.y);
      sm.z += __expf(Areg[k].z - rk - mx.z);
      sm.w += __expf(Areg[k].w - rk - mx.w);
    }
    *(float4*)&pm[w][4*l]  = mx;
    *(float4*)&psm[w][4*l] = sm;
    __syncthreads();
    // ---- combine 16 wave-partials per column ----
    if (t < 256){
      float m = pm[0][t], s = psm[0][t];
      #pragma unroll
      for (int ww=1; ww<16; ww++){
        float m2 = pm[ww][t], s2 = psm[ww][t];
        float mn = fmaxf(m, m2);
        s = s*__expf(m-mn) + s2*__expf(m2-mn);
        m = mn;
      }
      cv[t] = m + __logf(s);
    }
    __syncthreads();
  }
  // ---- plan = exp(A - r - c), in place ----
  float4 c4 = *(const float4*)&cv[4*l];
  #pragma unroll
  for (int k=0;k<16;k++){
    float rk = rv[rbase+k];
    float4 p;
    p.x = __expf(Areg[k].x - rk - c4.x);
    p.y = __expf(Areg[k].y - rk - c4.y);
    p.z = __expf(Areg[k].z - rk - c4.z);
    p.w = __expf(Areg[k].w - rk - c4.w);
    *(float4*)&A[(size_t)(rbase+k)*256 + 4*l] = p;
  }
}

// ---------------- loss: -sum relu(q - plan @ c)  (plan precomputed) ----------------
__global__ void __launch_bounds__(256) k_loss(const float* __restrict__ plan,
    const float* __restrict__ ef, float* __restrict__ out){
  __shared__ float ps[32][32];
  __shared__ float cs[32][256];
  __shared__ float red[4];
  int bid = blockIdx.x;
  int p = bid>>3, i0 = (bid&7)*32;
  int t = threadIdx.x;
  float acc[32];
  #pragma unroll
  for (int r=0;r<32;r++) acc[r]=0.f;
  const float* lap  = plan + (size_t)p*65536;
  const float* crow = ef + (size_t)(2*p+1)*EPG*MSGD;
  for (int kt=0; kt<EPG; kt+=32){
    __syncthreads();
    for (int i=t;i<32*32;i+=256){
      int r = i>>5, k = i&31;
      ps[r][k] = (kt+k < EPG) ? lap[(size_t)(i0+r)*256 + kt+k] : 0.f;
    }
    for (int i=t;i<32*256;i+=256){
      int k = i>>8, f = i&255;
      cs[k][f] = (kt+k < EPG) ? crow[(size_t)(kt+k)*MSGD + f] : 0.f;
    }
    __syncthreads();
    for (int k=0;k<32;k++){
      float cv = cs[k][t];
      #pragma unroll
      for (int r=0;r<32;r++) acc[r] = fmaf(ps[r][k], cv, acc[r]);
    }
  }
  const float* qrow = ef + (size_t)(2*p)*EPG*MSGD;
  float s = 0.f;
  #pragma unroll
  for (int r=0;r<32;r++){
    int row = i0+r;
    float q = (row < EPG) ? qrow[(size_t)row*MSGD + t] : 0.f;
    s += fmaxf(q - acc[r], 0.f);
  }
  #pragma unroll
  for (int off=32; off; off>>=1) s += __shfl_xor(s, off);
  if ((t&63)==0) red[t>>6]=s;
  __syncthreads();
  if (t==0) atomicAdd(&out[p], -(red[0]+red[1]+red[2]+red[3]));
}

// ---------------- launch ----------------
extern "C" void kernel_launch(void* const* d_in, const int* in_sizes, int n_in,
                              void* d_out, int out_size, void* d_ws, size_t ws_size,
                              hipStream_t stream){
  const float* nf   = (const float*)d_in[0];
  const float* ef   = (const float*)d_in[1];
  const int*   fidx = (const int*)d_in[2];
  const int*   tidx = (const int*)d_in[3];
  const float* enw  = (const float*)d_in[4];
  const float* enb  = (const float*)d_in[5];
  const float* eew  = (const float*)d_in[6];
  const float* eeb  = (const float*)d_in[7];
  const float* mw1  = (const float*)d_in[8];
  const float* mb1  = (const float*)d_in[9];
  const float* mw2  = (const float*)d_in[10];
  const float* mb2  = (const float*)d_in[11];
  const float* rw1  = (const float*)d_in[12];
  const float* rb1  = (const float*)d_in[13];
  const float* rw2  = (const float*)d_in[14];
  const float* rb2  = (const float*)d_in[15];
  const float* wih  = (const float*)d_in[16];
  const float* bih  = (const float*)d_in[17];
  const float* whh  = (const float*)d_in[18];
  const float* bhh  = (const float*)d_in[19];
  const float* skw1 = (const float*)d_in[20];
  const float* skb1 = (const float*)d_in[21];
  const float* skw2 = (const float*)d_in[22];
  const float* skb2 = (const float*)d_in[23];
  float* out = (float*)d_out;

  float* ws = (float*)d_ws;
  float* h_a    = ws;
  float* h_b    = h_a + (size_t)NN*HD;
  float* e_enc  = h_b + (size_t)NN*HD;
  float* e_fin  = e_enc + (size_t)NE*EED;
  float* agg    = e_fin;                           // aliases e_fin (loop phase only)
  float* t_all  = e_fin + (size_t)NE*MSGD;
  float* la     = t_all + (size_t)NG*256*SKD;

  short* w1f_p = (short*)la;
  short* w1r_p = w1f_p + 320*256;
  short* w2f_p = w1r_p + 320*256;
  short* w2r_p = w2f_p + 256*256;

  k_pack<<<40, 256, 0, stream>>>(mw1, w1f_p, 320);
  k_pack<<<40, 256, 0, stream>>>(rw1, w1r_p, 320);
  k_pack<<<32, 256, 0, stream>>>(mw2, w2f_p, 256);
  k_pack<<<32, 256, 0, stream>>>(rw2, w2r_p, 256);

  k_enc_node<<<NN/2, 256, 0, stream>>>(nf, enw, enb, h_a);
  k_enc_edge<<<NE/4, 256, 0, stream>>>(ef, eew, eeb, e_enc);

  float* hc = h_a; float* hn = h_b;
  for (int step=0; step<5; step++){
    hipMemsetAsync(agg, 0, (size_t)NN*MSGD*sizeof(float), stream);
    k_msg<false><<<NE/64, 256, 0, stream>>>(hc, e_enc, fidx, tidx,
        w1f_p, mb1, w2f_p, mb2, w1r_p, rb1, w2r_p, rb2, agg);
    k_gru<<<NN/16, 384, 0, stream>>>(hc, agg, wih, bih, whh, bhh, hn);
    float* tmp = hc; hc = hn; hn = tmp;
  }
  k_msg<true><<<NE/64, 256, 0, stream>>>(hc, e_enc, fidx, tidx,
      w1f_p, mb1, w2f_p, mb2, w1r_p, rb1, w2r_p, rb2, e_fin);

  k_tall<<<NG*32, 256, 0, stream>>>(e_fin, skw1, skb1, skw2, skb2, t_all);
  k_lainit<<<NP, 256, 0, stream>>>(t_all, la);
  k_sinkhorn<<<NP, 1024, 0, stream>>>(la);

  hipMemsetAsync(out, 0, (size_t)NP*sizeof(float), stream);
  k_loss<<<NP*8, 256, 0, stream>>>(la, e_fin, out);
}

// Round 4
// 2193.970 us; speedup vs baseline: 8.5916x; 1.6819x over previous
//
#include <hip/hip_runtime.h>
#include <math.h>

typedef __attribute__((ext_vector_type(4))) float f32x4;
typedef __attribute__((ext_vector_type(8))) short s16x8;

#define NN 32768      // nodes
#define NE 102400     // edges
#define HD 128        // H
#define EED 64        // edge enc dim
#define MSGD 256
#define NG 512        // graphs
#define EPG 200       // edges per graph
#define NP 256        // pairs
#define SKD 32

__device__ inline short f2bf(float x){
  union{float f; unsigned u;} z; z.f=x;
  unsigned r = (z.u + 0x7fffu + ((z.u>>16)&1u)) >> 16;
  return (short)r;
}

// ---------------- node encoder: h = nf @ Wn + bn ----------------
__global__ void __launch_bounds__(256) k_enc_node(const float* __restrict__ nf,
    const float* __restrict__ W, const float* __restrict__ b, float* __restrict__ h){
  __shared__ float Ws[16*128];
  int t = threadIdx.x;
  for (int i=t;i<16*128;i+=256) Ws[i]=W[i];
  __syncthreads();
  int node = blockIdx.x*2 + (t>>7);
  int f = t & 127;
  const float* x = nf + node*16;
  float acc = b[f];
  #pragma unroll
  for (int k=0;k<16;k++) acc = fmaf(x[k], Ws[k*128+f], acc);
  h[node*HD+f] = acc;
}

// ---------------- edge encoder: e = ef @ We + be ----------------
__global__ void __launch_bounds__(256) k_enc_edge(const float* __restrict__ ef,
    const float* __restrict__ W, const float* __restrict__ b, float* __restrict__ ee){
  __shared__ float Ws[16*64];
  int t = threadIdx.x;
  for (int i=t;i<16*64;i+=256) Ws[i]=W[i];
  __syncthreads();
  int edge = blockIdx.x*4 + (t>>6);
  int f = t & 63;
  const float* x = ef + edge*16;
  float acc = b[f];
  #pragma unroll
  for (int k=0;k<16;k++) acc = fmaf(x[k], Ws[k*64+f], acc);
  ee[edge*EED+f] = acc;
}

// ---------------- weight pack: W[K][N] f32 -> bf16 MFMA B-frag order ----------------
// dst[((kt*(N/16)+nt)*64+l)*8+j] = bf16(W[(kt*32+(l>>4)*8+j)*N + nt*16+(l&15)])
__global__ void __launch_bounds__(256) k_pack(const float* __restrict__ W,
    short* __restrict__ dst, int K, int N){
  int NT = N >> 4;
  int i = blockIdx.x*256 + threadIdx.x;
  if (i >= (K/32)*NT*64) return;
  int l = i & 63, tile = i >> 6;
  int nt = tile % NT, kt = tile / NT;
  int lr = l & 15, lq = l >> 4;
  s16x8 v;
  #pragma unroll
  for (int j=0;j<8;j++)
    v[j] = f2bf(W[(size_t)(kt*32 + lq*8 + j)*N + nt*16 + lr]);
  *((s16x8*)dst + i) = v;
}

// ---------------- message MLPs (fwd+rev), bf16 MFMA ----------------
template<bool FINAL>
__global__ void __launch_bounds__(256,2) k_msg(const float* __restrict__ h,
    const float* __restrict__ ee, const int* __restrict__ from_idx, const int* __restrict__ to_idx,
    const short* __restrict__ w1f, const float* __restrict__ b1f,
    const short* __restrict__ w2f, const float* __restrict__ b2f,
    const short* __restrict__ w1r, const float* __restrict__ b1r,
    const short* __restrict__ w2r, const float* __restrict__ b2r,
    float* __restrict__ outp){
  __shared__ __align__(16) short Xs[64][328];
  __shared__ __align__(16) short Ys[64][264];
  __shared__ int sidx[64], didx[64];
  int t = threadIdx.x;
  int e0 = blockIdx.x*64;
  if (t < 64){ sidx[t]=from_idx[e0+t]; didx[t]=to_idx[e0+t]; }
  __syncthreads();
  for (int i=t; i<64*40; i+=256){
    int r = i/40, c8 = (i - r*40)*8;
    const float* src; int off;
    if (c8 < 128){ src = h + (size_t)sidx[r]*HD; off = c8; }
    else if (c8 < 256){ src = h + (size_t)didx[r]*HD; off = c8-128; }
    else { src = ee + (size_t)(e0+r)*EED; off = c8-256; }
    float4 a = *(const float4*)(src+off);
    float4 b = *(const float4*)(src+off+4);
    s16x8 v;
    v[0]=f2bf(a.x); v[1]=f2bf(a.y); v[2]=f2bf(a.z); v[3]=f2bf(a.w);
    v[4]=f2bf(b.x); v[5]=f2bf(b.y); v[6]=f2bf(b.z); v[7]=f2bf(b.w);
    *(s16x8*)&Xs[r][c8] = v;
  }
  __syncthreads();

  int wv = t>>6, l = t&63, lr = l&15, lq = l>>4;
  int cbase = wv*64;

  f32x4 fsv[4][4];

  for (int dir=0; dir<2; dir++){
    const s16x8* W1v = (const s16x8*)(dir ? w1r : w1f);
    const float* B1  = dir ? b1r : b1f;
    const s16x8* W2v = (const s16x8*)(dir ? w2r : w2f);
    const float* B2  = dir ? b2r : b2f;

    f32x4 acc[4][4];
    #pragma unroll
    for (int ct=0; ct<4; ct++){
      float bb = B1[cbase + ct*16 + lr];
      #pragma unroll
      for (int rt=0; rt<4; rt++) acc[rt][ct] = (f32x4){bb,bb,bb,bb};
    }
    for (int kt=0; kt<10; kt++){
      int sc = (dir && kt<8) ? (kt^4) : kt;
      s16x8 af[4], bfr[4];
      #pragma unroll
      for (int rt=0; rt<4; rt++) af[rt] = *(const s16x8*)&Xs[rt*16+lr][sc*32 + lq*8];
      #pragma unroll
      for (int ct=0; ct<4; ct++) bfr[ct] = W1v[(size_t)(kt*16 + wv*4 + ct)*64 + l];
      #pragma unroll
      for (int rt=0; rt<4; rt++)
        #pragma unroll
        for (int ct=0; ct<4; ct++)
          acc[rt][ct] = __builtin_amdgcn_mfma_f32_16x16x32_bf16(af[rt], bfr[ct], acc[rt][ct], 0,0,0);
    }
    #pragma unroll
    for (int rt=0; rt<4; rt++)
      #pragma unroll
      for (int ct=0; ct<4; ct++)
        #pragma unroll
        for (int r=0; r<4; r++)
          Ys[rt*16 + lq*4 + r][cbase + ct*16 + lr] = f2bf(fmaxf(acc[rt][ct][r], 0.f));
    __syncthreads();

    f32x4 acc2[4][4];
    #pragma unroll
    for (int ct=0; ct<4; ct++){
      float bb = B2[cbase + ct*16 + lr];
      #pragma unroll
      for (int rt=0; rt<4; rt++) acc2[rt][ct] = (f32x4){bb,bb,bb,bb};
    }
    for (int kt=0; kt<8; kt++){
      s16x8 af[4], bfr[4];
      #pragma unroll
      for (int rt=0; rt<4; rt++) af[rt] = *(const s16x8*)&Ys[rt*16+lr][kt*32 + lq*8];
      #pragma unroll
      for (int ct=0; ct<4; ct++) bfr[ct] = W2v[(size_t)(kt*16 + wv*4 + ct)*64 + l];
      #pragma unroll
      for (int rt=0; rt<4; rt++)
        #pragma unroll
        for (int ct=0; ct<4; ct++)
          acc2[rt][ct] = __builtin_amdgcn_mfma_f32_16x16x32_bf16(af[rt], bfr[ct], acc2[rt][ct], 0,0,0);
    }

    if (FINAL){
      if (dir==0){
        #pragma unroll
        for (int rt=0; rt<4; rt++)
          #pragma unroll
          for (int ct=0; ct<4; ct++) fsv[rt][ct] = acc2[rt][ct];
      } else {
        #pragma unroll
        for (int rt=0; rt<4; rt++)
          #pragma unroll
          for (int ct=0; ct<4; ct++)
            #pragma unroll
            for (int r=0; r<4; r++){
              int row = e0 + rt*16 + lq*4 + r;
              outp[(size_t)row*MSGD + cbase + ct*16 + lr] = fsv[rt][ct][r] + acc2[rt][ct][r];
            }
      }
    } else {
      const int* gidx = dir ? sidx : didx;
      #pragma unroll
      for (int rt=0; rt<4; rt++)
        #pragma unroll
        for (int ct=0; ct<4; ct++)
          #pragma unroll
          for (int r=0; r<4; r++){
            int row = rt*16 + lq*4 + r;
            atomicAdd(&outp[(size_t)gidx[row]*MSGD + cbase + ct*16 + lr], acc2[rt][ct][r]);
          }
    }
    __syncthreads();
  }
}

// ---------------- GRU, bf16 MFMA, gate-aligned column tiles ----------------
// 64 nodes/block, 4 waves. Wave w owns col tiles {chunk*8 + 2w + j} for
// chunk in {r,z,n}, j in {0,1} -> same 32-col window of each gate chunk ->
// gates computed fully in-register (f32 accumulators, no LDS round trip).
__global__ void __launch_bounds__(256,2) k_gru(const float* __restrict__ h,
    const float* __restrict__ agg,
    const short* __restrict__ wih_p, const float* __restrict__ bih,
    const short* __restrict__ whh_p, const float* __restrict__ bhh,
    float* __restrict__ hnew){
  __shared__ __align__(16) short aggs[64][264];  // 33792 B
  __shared__ __align__(16) short hs[64][136];    // 17408 B
  int t = threadIdx.x;
  int n0 = blockIdx.x*64;
  for (int i=t; i<64*32; i+=256){
    int r = i>>5, c8 = (i&31)*8;
    float4 a = *(const float4*)&agg[(size_t)(n0+r)*MSGD + c8];
    float4 b = *(const float4*)&agg[(size_t)(n0+r)*MSGD + c8 + 4];
    s16x8 v;
    v[0]=f2bf(a.x); v[1]=f2bf(a.y); v[2]=f2bf(a.z); v[3]=f2bf(a.w);
    v[4]=f2bf(b.x); v[5]=f2bf(b.y); v[6]=f2bf(b.z); v[7]=f2bf(b.w);
    *(s16x8*)&aggs[r][c8] = v;
  }
  for (int i=t; i<64*16; i+=256){
    int r = i>>4, c8 = (i&15)*8;
    float4 a = *(const float4*)&h[(size_t)(n0+r)*HD + c8];
    float4 b = *(const float4*)&h[(size_t)(n0+r)*HD + c8 + 4];
    s16x8 v;
    v[0]=f2bf(a.x); v[1]=f2bf(a.y); v[2]=f2bf(a.z); v[3]=f2bf(a.w);
    v[4]=f2bf(b.x); v[5]=f2bf(b.y); v[6]=f2bf(b.z); v[7]=f2bf(b.w);
    *(s16x8*)&hs[r][c8] = v;
  }
  __syncthreads();

  int wv = t>>6, l = t&63, lr = l&15, lq = l>>4;
  const s16x8* Wih_v = (const s16x8*)wih_p;
  const s16x8* Whh_v = (const s16x8*)whh_p;

  f32x4 gi[4][6], gh[4][6];
  #pragma unroll
  for (int ct=0; ct<6; ct++){
    int bcol = (ct>>1)*128 + wv*32 + (ct&1)*16 + lr;
    float bi = bih[bcol], bh = bhh[bcol];
    #pragma unroll
    for (int rt=0; rt<4; rt++){
      gi[rt][ct] = (f32x4){bi,bi,bi,bi};
      gh[rt][ct] = (f32x4){bh,bh,bh,bh};
    }
  }
  // gi = agg @ Wih : K=256
  for (int kt=0; kt<8; kt++){
    s16x8 af[4], bfr[6];
    #pragma unroll
    for (int rt=0; rt<4; rt++) af[rt] = *(const s16x8*)&aggs[rt*16+lr][kt*32 + lq*8];
    #pragma unroll
    for (int ct=0; ct<6; ct++){
      int nt = (ct>>1)*8 + wv*2 + (ct&1);
      bfr[ct] = Wih_v[(size_t)(kt*24 + nt)*64 + l];
    }
    #pragma unroll
    for (int rt=0; rt<4; rt++)
      #pragma unroll
      for (int ct=0; ct<6; ct++)
        gi[rt][ct] = __builtin_amdgcn_mfma_f32_16x16x32_bf16(af[rt], bfr[ct], gi[rt][ct], 0,0,0);
  }
  // gh = h @ Whh : K=128
  for (int kt=0; kt<4; kt++){
    s16x8 af[4], bfr[6];
    #pragma unroll
    for (int rt=0; rt<4; rt++) af[rt] = *(const s16x8*)&hs[rt*16+lr][kt*32 + lq*8];
    #pragma unroll
    for (int ct=0; ct<6; ct++){
      int nt = (ct>>1)*8 + wv*2 + (ct&1);
      bfr[ct] = Whh_v[(size_t)(kt*24 + nt)*64 + l];
    }
    #pragma unroll
    for (int rt=0; rt<4; rt++)
      #pragma unroll
      for (int ct=0; ct<6; ct++)
        gh[rt][ct] = __builtin_amdgcn_mfma_f32_16x16x32_bf16(af[rt], bfr[ct], gh[rt][ct], 0,0,0);
  }
  // gates in-register; h_old read f32 from global (exact)
  #pragma unroll
  for (int rt=0; rt<4; rt++)
    #pragma unroll
    for (int j=0; j<2; j++)
      #pragma unroll
      for (int r=0; r<4; r++){
        int row = n0 + rt*16 + lq*4 + r;
        int col = wv*32 + j*16 + lr;
        float rr = 1.f/(1.f + __expf(-(gi[rt][j][r]   + gh[rt][j][r])));
        float zz = 1.f/(1.f + __expf(-(gi[rt][2+j][r] + gh[rt][2+j][r])));
        float gn = gi[rt][4+j][r] + rr*gh[rt][4+j][r];
        float nn = 1.f - 2.f/(__expf(2.f*gn) + 1.f);   // tanh
        float hold = h[(size_t)row*HD + col];
        hnew[(size_t)row*HD + col] = (1.f - zz)*nn + zz*hold;
      }
}

// ---------------- SK transform ----------------
__global__ void __launch_bounds__(256) k_tall(const float* __restrict__ ef,
    const float* __restrict__ W1, const float* __restrict__ b1,
    const float* __restrict__ W2, const float* __restrict__ b2,
    float* __restrict__ tall){
  __shared__ float W1s[256*32];
  __shared__ float W2s[32*32];
  __shared__ float b1s[32], b2s[32];
  __shared__ float xsr[8][256];
  __shared__ float y1s[8][32];
  int t = threadIdx.x;
  for (int i=t;i<256*32;i+=256) W1s[i]=W1[i];
  for (int i=t;i<32*32;i+=256)  W2s[i]=W2[i];
  if (t<32){ b1s[t]=b1[t]; b2s[t]=b2[t]; }
  int g = blockIdx.x >> 5;
  int i0 = (blockIdx.x & 31)*8;
  for (int i=t;i<8*256;i+=256){
    int r = i>>8, k = i&255;
    int row = i0+r;
    xsr[r][k] = (row < EPG) ? ef[((size_t)g*EPG + row)*MSGD + k] : 0.f;
  }
  __syncthreads();
  int r = t>>5, c = t&31;
  float acc = b1s[c];
  for (int k=0;k<256;k+=4){
    const float4 x4 = *(const float4*)&xsr[r][k];
    acc = fmaf(x4.x,W1s[(k+0)*32+c], fmaf(x4.y,W1s[(k+1)*32+c],
          fmaf(x4.z,W1s[(k+2)*32+c], fmaf(x4.w,W1s[(k+3)*32+c], acc))));
  }
  y1s[r][c] = fmaxf(acc, 0.f);
  __syncthreads();
  float acc2 = b2s[c];
  #pragma unroll
  for (int k=0;k<32;k++) acc2 = fmaf(y1s[r][k], W2s[k*32+c], acc2);
  int row = i0+r;
  tall[((size_t)g*256 + row)*SKD + c] = (row < EPG) ? acc2 : 0.f;
}

// ---------------- la init ----------------
__global__ void __launch_bounds__(256) k_lainit(const float* __restrict__ tall,
    float* __restrict__ la){
  __shared__ float tqs[256*32];
  __shared__ float tcs[256*32];
  int p = blockIdx.x, t = threadIdx.x;
  const float* tq = tall + (size_t)(2*p)*8192;
  const float* tc = tall + (size_t)(2*p+1)*8192;
  for (int i=t;i<8192;i+=256){ tqs[i]=tq[i]; tcs[i]=tc[i]; }
  __syncthreads();
  float creg[32];
  #pragma unroll
  for (int k=0;k<32;k++) creg[k]=tcs[t*32+k];
  float* out = la + (size_t)p*65536;
  for (int i=0;i<256;i++){
    float acc = 0.f;
    #pragma unroll
    for (int k=0;k<32;k+=4){
      const float4 q4 = *(const float4*)&tqs[i*32+k];
      acc = fmaf(q4.x,creg[k], fmaf(q4.y,creg[k+1], fmaf(q4.z,creg[k+2], fmaf(q4.w,creg[k+3], acc))));
    }
    out[(size_t)i*256 + t] = acc * 10.0f;
  }
}

// ---------------- Sinkhorn: register-resident, r/c reformulation ----------------
__global__ void __launch_bounds__(1024) k_sinkhorn(float* __restrict__ la){
  __shared__ float cv[256];
  __shared__ float rv[256];
  __shared__ float pm[16][256];
  __shared__ float psm[16][256];
  int t = threadIdx.x;
  int w = t>>6, l = t&63;
  int rbase = w*16;
  float* A = la + (size_t)blockIdx.x*65536;
  float4 Areg[16];
  #pragma unroll
  for (int k=0;k<16;k++)
    Areg[k] = *(const float4*)&A[(size_t)(rbase+k)*256 + 4*l];
  if (t < 256) cv[t] = 0.f;
  __syncthreads();

  for (int it=0; it<20; it++){
    float4 c4 = *(const float4*)&cv[4*l];
    #pragma unroll
    for (int k=0;k<16;k++){
      float4 v;
      v.x = Areg[k].x - c4.x; v.y = Areg[k].y - c4.y;
      v.z = Areg[k].z - c4.z; v.w = Areg[k].w - c4.w;
      float m = fmaxf(fmaxf(v.x,v.y), fmaxf(v.z,v.w));
      #pragma unroll
      for (int off=32; off; off>>=1) m = fmaxf(m, __shfl_xor(m, off));
      float s = __expf(v.x-m)+__expf(v.y-m)+__expf(v.z-m)+__expf(v.w-m);
      #pragma unroll
      for (int off=32; off; off>>=1) s += __shfl_xor(s, off);
      if (l==0) rv[rbase+k] = m + __logf(s);
    }
    float4 mx = {-INFINITY,-INFINITY,-INFINITY,-INFINITY};
    #pragma unroll
    for (int k=0;k<16;k++){
      float rk = rv[rbase+k];
      mx.x = fmaxf(mx.x, Areg[k].x - rk);
      mx.y = fmaxf(mx.y, Areg[k].y - rk);
      mx.z = fmaxf(mx.z, Areg[k].z - rk);
      mx.w = fmaxf(mx.w, Areg[k].w - rk);
    }
    float4 sm = {0.f,0.f,0.f,0.f};
    #pragma unroll
    for (int k=0;k<16;k++){
      float rk = rv[rbase+k];
      sm.x += __expf(Areg[k].x - rk - mx.x);
      sm.y += __expf(Areg[k].y - rk - mx.y);
      sm.z += __expf(Areg[k].z - rk - mx.z);
      sm.w += __expf(Areg[k].w - rk - mx.w);
    }
    *(float4*)&pm[w][4*l]  = mx;
    *(float4*)&psm[w][4*l] = sm;
    __syncthreads();
    if (t < 256){
      float m = pm[0][t], s = psm[0][t];
      #pragma unroll
      for (int ww=1; ww<16; ww++){
        float m2 = pm[ww][t], s2 = psm[ww][t];
        float mn = fmaxf(m, m2);
        s = s*__expf(m-mn) + s2*__expf(m2-mn);
        m = mn;
      }
      cv[t] = m + __logf(s);
    }
    __syncthreads();
  }
  float4 c4 = *(const float4*)&cv[4*l];
  #pragma unroll
  for (int k=0;k<16;k++){
    float rk = rv[rbase+k];
    float4 p;
    p.x = __expf(Areg[k].x - rk - c4.x);
    p.y = __expf(Areg[k].y - rk - c4.y);
    p.z = __expf(Areg[k].z - rk - c4.z);
    p.w = __expf(Areg[k].w - rk - c4.w);
    *(float4*)&A[(size_t)(rbase+k)*256 + 4*l] = p;
  }
}

// ---------------- loss: -sum relu(q - plan @ c) ----------------
__global__ void __launch_bounds__(256) k_loss(const float* __restrict__ plan,
    const float* __restrict__ ef, float* __restrict__ out){
  __shared__ float ps[32][32];
  __shared__ float cs[32][256];
  __shared__ float red[4];
  int bid = blockIdx.x;
  int p = bid>>3, i0 = (bid&7)*32;
  int t = threadIdx.x;
  float acc[32];
  #pragma unroll
  for (int r=0;r<32;r++) acc[r]=0.f;
  const float* lap  = plan + (size_t)p*65536;
  const float* crow = ef + (size_t)(2*p+1)*EPG*MSGD;
  for (int kt=0; kt<EPG; kt+=32){
    __syncthreads();
    for (int i=t;i<32*32;i+=256){
      int r = i>>5, k = i&31;
      ps[r][k] = (kt+k < EPG) ? lap[(size_t)(i0+r)*256 + kt+k] : 0.f;
    }
    for (int i=t;i<32*256;i+=256){
      int k = i>>8, f = i&255;
      cs[k][f] = (kt+k < EPG) ? crow[(size_t)(kt+k)*MSGD + f] : 0.f;
    }
    __syncthreads();
    for (int k=0;k<32;k++){
      float cv = cs[k][t];
      #pragma unroll
      for (int r=0;r<32;r++) acc[r] = fmaf(ps[r][k], cv, acc[r]);
    }
  }
  const float* qrow = ef + (size_t)(2*p)*EPG*MSGD;
  float s = 0.f;
  #pragma unroll
  for (int r=0;r<32;r++){
    int row = i0+r;
    float q = (row < EPG) ? qrow[(size_t)row*MSGD + t] : 0.f;
    s += fmaxf(q - acc[r], 0.f);
  }
  #pragma unroll
  for (int off=32; off; off>>=1) s += __shfl_xor(s, off);
  if ((t&63)==0) red[t>>6]=s;
  __syncthreads();
  if (t==0) atomicAdd(&out[p], -(red[0]+red[1]+red[2]+red[3]));
}

// ---------------- launch ----------------
extern "C" void kernel_launch(void* const* d_in, const int* in_sizes, int n_in,
                              void* d_out, int out_size, void* d_ws, size_t ws_size,
                              hipStream_t stream){
  const float* nf   = (const float*)d_in[0];
  const float* ef   = (const float*)d_in[1];
  const int*   fidx = (const int*)d_in[2];
  const int*   tidx = (const int*)d_in[3];
  const float* enw  = (const float*)d_in[4];
  const float* enb  = (const float*)d_in[5];
  const float* eew  = (const float*)d_in[6];
  const float* eeb  = (const float*)d_in[7];
  const float* mw1  = (const float*)d_in[8];
  const float* mb1  = (const float*)d_in[9];
  const float* mw2  = (const float*)d_in[10];
  const float* mb2  = (const float*)d_in[11];
  const float* rw1  = (const float*)d_in[12];
  const float* rb1  = (const float*)d_in[13];
  const float* rw2  = (const float*)d_in[14];
  const float* rb2  = (const float*)d_in[15];
  const float* wih  = (const float*)d_in[16];
  const float* bih  = (const float*)d_in[17];
  const float* whh  = (const float*)d_in[18];
  const float* bhh  = (const float*)d_in[19];
  const float* skw1 = (const float*)d_in[20];
  const float* skb1 = (const float*)d_in[21];
  const float* skw2 = (const float*)d_in[22];
  const float* skb2 = (const float*)d_in[23];
  float* out = (float*)d_out;

  float* ws = (float*)d_ws;
  float* h_a    = ws;
  float* h_b    = h_a + (size_t)NN*HD;
  float* e_enc  = h_b + (size_t)NN*HD;
  float* e_fin  = e_enc + (size_t)NE*EED;
  float* agg    = e_fin;                           // aliases e_fin (loop phase only)
  float* t_all  = e_fin + (size_t)NE*MSGD;
  float* la     = t_all + (size_t)NG*256*SKD;

  // packed bf16 weights alias la (la written only after all k_msg/k_gru done)
  short* w1f_p = (short*)la;
  short* w1r_p = w1f_p + 320*256;
  short* w2f_p = w1r_p + 320*256;
  short* w2r_p = w2f_p + 256*256;
  short* wih_p = w2r_p + 256*256;
  short* whh_p = wih_p + 256*384;

  k_pack<<<40, 256, 0, stream>>>(mw1, w1f_p, 320, 256);
  k_pack<<<40, 256, 0, stream>>>(rw1, w1r_p, 320, 256);
  k_pack<<<32, 256, 0, stream>>>(mw2, w2f_p, 256, 256);
  k_pack<<<32, 256, 0, stream>>>(rw2, w2r_p, 256, 256);
  k_pack<<<48, 256, 0, stream>>>(wih, wih_p, 256, 384);
  k_pack<<<24, 256, 0, stream>>>(whh, whh_p, 128, 384);

  k_enc_node<<<NN/2, 256, 0, stream>>>(nf, enw, enb, h_a);
  k_enc_edge<<<NE/4, 256, 0, stream>>>(ef, eew, eeb, e_enc);

  float* hc = h_a; float* hn = h_b;
  for (int step=0; step<5; step++){
    hipMemsetAsync(agg, 0, (size_t)NN*MSGD*sizeof(float), stream);
    k_msg<false><<<NE/64, 256, 0, stream>>>(hc, e_enc, fidx, tidx,
        w1f_p, mb1, w2f_p, mb2, w1r_p, rb1, w2r_p, rb2, agg);
    k_gru<<<NN/64, 256, 0, stream>>>(hc, agg, wih_p, bih, whh_p, bhh, hn);
    float* tmp = hc; hc = hn; hn = tmp;
  }
  k_msg<true><<<NE/64, 256, 0, stream>>>(hc, e_enc, fidx, tidx,
      w1f_p, mb1, w2f_p, mb2, w1r_p, rb1, w2r_p, rb2, e_fin);

  k_tall<<<NG*32, 256, 0, stream>>>(e_fin, skw1, skb1, skw2, skb2, t_all);
  k_lainit<<<NP, 256, 0, stream>>>(t_all, la);
  k_sinkhorn<<<NP, 1024, 0, stream>>>(la);

  hipMemsetAsync(out, 0, (size_t)NP*sizeof(float), stream);
  k_loss<<<NP*8, 256, 0, stream>>>(la, e_fin, out);
}

// Round 5
// 2081.851 us; speedup vs baseline: 9.0543x; 1.0539x over previous
//
#include <hip/hip_runtime.h>
#include <math.h>

typedef __attribute__((ext_vector_type(4))) float f32x4;
typedef __attribute__((ext_vector_type(8))) short s16x8;

#define NN 32768      // nodes
#define NE 102400     // edges
#define HD 128        // H
#define EED 64        // edge enc dim
#define MSGD 256
#define NG 512        // graphs
#define EPG 200       // edges per graph
#define NP 256        // pairs
#define SKD 32

__device__ inline short f2bf(float x){
  union{float f; unsigned u;} z; z.f=x;
  unsigned r = (z.u + 0x7fffu + ((z.u>>16)&1u)) >> 16;
  return (short)r;
}

// ---------------- node encoder: h = nf @ Wn + bn ----------------
__global__ void __launch_bounds__(256) k_enc_node(const float* __restrict__ nf,
    const float* __restrict__ W, const float* __restrict__ b, float* __restrict__ h){
  __shared__ float Ws[16*128];
  int t = threadIdx.x;
  for (int i=t;i<16*128;i+=256) Ws[i]=W[i];
  __syncthreads();
  int node = blockIdx.x*2 + (t>>7);
  int f = t & 127;
  const float* x = nf + node*16;
  float acc = b[f];
  #pragma unroll
  for (int k=0;k<16;k++) acc = fmaf(x[k], Ws[k*128+f], acc);
  h[node*HD+f] = acc;
}

// ---------------- edge encoder: e = ef @ We + be ----------------
__global__ void __launch_bounds__(256) k_enc_edge(const float* __restrict__ ef,
    const float* __restrict__ W, const float* __restrict__ b, float* __restrict__ ee){
  __shared__ float Ws[16*64];
  int t = threadIdx.x;
  for (int i=t;i<16*64;i+=256) Ws[i]=W[i];
  __syncthreads();
  int edge = blockIdx.x*4 + (t>>6);
  int f = t & 63;
  const float* x = ef + edge*16;
  float acc = b[f];
  #pragma unroll
  for (int k=0;k<16;k++) acc = fmaf(x[k], Ws[k*64+f], acc);
  ee[edge*EED+f] = acc;
}

// ---------------- weight pack: W[K][N] f32 -> bf16 MFMA B-frag order ----------------
__global__ void __launch_bounds__(256) k_pack(const float* __restrict__ W,
    short* __restrict__ dst, int K, int N){
  int NT = N >> 4;
  int i = blockIdx.x*256 + threadIdx.x;
  if (i >= (K/32)*NT*64) return;
  int l = i & 63, tile = i >> 6;
  int nt = tile % NT, kt = tile / NT;
  int lr = l & 15, lq = l >> 4;
  s16x8 v;
  #pragma unroll
  for (int j=0;j<8;j++)
    v[j] = f2bf(W[(size_t)(kt*32 + lq*8 + j)*N + nt*16 + lr]);
  *((s16x8*)dst + i) = v;
}

// ---------------- message MLPs (fwd+rev), bf16 MFMA, pipelined ----------------
template<bool FINAL>
__global__ void __launch_bounds__(256,2) k_msg(const float* __restrict__ h,
    const float* __restrict__ ee, const int* __restrict__ from_idx, const int* __restrict__ to_idx,
    const short* __restrict__ w1f, const float* __restrict__ b1f,
    const short* __restrict__ w2f, const float* __restrict__ b2f,
    const short* __restrict__ w1r, const float* __restrict__ b1r,
    const short* __restrict__ w2r, const float* __restrict__ b2r,
    float* __restrict__ outp){
  __shared__ __align__(16) short Xs[64][328];
  __shared__ __align__(16) short Ys[64][264];
  __shared__ int sidx[64], didx[64];
  int t = threadIdx.x;
  int e0 = blockIdx.x*64;
  if (t < 64){ sidx[t]=from_idx[e0+t]; didx[t]=to_idx[e0+t]; }
  __syncthreads();
  for (int i=t; i<64*40; i+=256){
    int r = i/40, c8 = (i - r*40)*8;
    const float* src; int off;
    if (c8 < 128){ src = h + (size_t)sidx[r]*HD; off = c8; }
    else if (c8 < 256){ src = h + (size_t)didx[r]*HD; off = c8-128; }
    else { src = ee + (size_t)(e0+r)*EED; off = c8-256; }
    float4 a = *(const float4*)(src+off);
    float4 b = *(const float4*)(src+off+4);
    s16x8 v;
    v[0]=f2bf(a.x); v[1]=f2bf(a.y); v[2]=f2bf(a.z); v[3]=f2bf(a.w);
    v[4]=f2bf(b.x); v[5]=f2bf(b.y); v[6]=f2bf(b.z); v[7]=f2bf(b.w);
    *(s16x8*)&Xs[r][c8] = v;
  }
  __syncthreads();

  int wv = t>>6, l = t&63, lr = l&15, lq = l>>4;
  int cbase = wv*64;

  f32x4 fsv[4][4];

  for (int dir=0; dir<2; dir++){
    const s16x8* W1v = (const s16x8*)(dir ? w1r : w1f);
    const float* B1  = dir ? b1r : b1f;
    const s16x8* W2v = (const s16x8*)(dir ? w2r : w2f);
    const float* B2  = dir ? b2r : b2f;

    f32x4 acc[4][4];
    #pragma unroll
    for (int ct=0; ct<4; ct++){
      float bb = B1[cbase + ct*16 + lr];
      #pragma unroll
      for (int rt=0; rt<4; rt++) acc[rt][ct] = (f32x4){bb,bb,bb,bb};
    }
    // layer 1: K=320, 10 k-steps; explicit prefetch (af depth 1, bfr depth 2)
    {
      s16x8 a0[4], b0[4], b1[4];
      {
        int sc0 = dir ? 4 : 0;
        #pragma unroll
        for (int rt=0;rt<4;rt++) a0[rt] = *(const s16x8*)&Xs[rt*16+lr][sc0*32 + lq*8];
        #pragma unroll
        for (int ct=0;ct<4;ct++) b0[ct] = W1v[(size_t)(0*16 + wv*4 + ct)*64 + l];
        #pragma unroll
        for (int ct=0;ct<4;ct++) b1[ct] = W1v[(size_t)(1*16 + wv*4 + ct)*64 + l];
      }
      #pragma unroll
      for (int kt=0; kt<10; kt++){
        s16x8 an[4], bn[4];
        if (kt < 9){
          int sc = (dir && (kt+1)<8) ? ((kt+1)^4) : (kt+1);
          #pragma unroll
          for (int rt=0;rt<4;rt++) an[rt] = *(const s16x8*)&Xs[rt*16+lr][sc*32 + lq*8];
        }
        if (kt < 8){
          #pragma unroll
          for (int ct=0;ct<4;ct++) bn[ct] = W1v[(size_t)((kt+2)*16 + wv*4 + ct)*64 + l];
        }
        #pragma unroll
        for (int rt=0; rt<4; rt++)
          #pragma unroll
          for (int ct=0; ct<4; ct++)
            acc[rt][ct] = __builtin_amdgcn_mfma_f32_16x16x32_bf16(a0[rt], b0[ct], acc[rt][ct], 0,0,0);
        #pragma unroll
        for (int i=0;i<4;i++){ a0[i]=an[i]; b0[i]=b1[i]; b1[i]=bn[i]; }
      }
    }
    #pragma unroll
    for (int rt=0; rt<4; rt++)
      #pragma unroll
      for (int ct=0; ct<4; ct++)
        #pragma unroll
        for (int r=0; r<4; r++)
          Ys[rt*16 + lq*4 + r][cbase + ct*16 + lr] = f2bf(fmaxf(acc[rt][ct][r], 0.f));
    __syncthreads();

    f32x4 acc2[4][4];
    #pragma unroll
    for (int ct=0; ct<4; ct++){
      float bb = B2[cbase + ct*16 + lr];
      #pragma unroll
      for (int rt=0; rt<4; rt++) acc2[rt][ct] = (f32x4){bb,bb,bb,bb};
    }
    // layer 2: K=256, 8 k-steps; same pipelining
    {
      s16x8 a0[4], b0[4], b1[4];
      {
        #pragma unroll
        for (int rt=0;rt<4;rt++) a0[rt] = *(const s16x8*)&Ys[rt*16+lr][lq*8];
        #pragma unroll
        for (int ct=0;ct<4;ct++) b0[ct] = W2v[(size_t)(0*16 + wv*4 + ct)*64 + l];
        #pragma unroll
        for (int ct=0;ct<4;ct++) b1[ct] = W2v[(size_t)(1*16 + wv*4 + ct)*64 + l];
      }
      #pragma unroll
      for (int kt=0; kt<8; kt++){
        s16x8 an[4], bn[4];
        if (kt < 7){
          #pragma unroll
          for (int rt=0;rt<4;rt++) an[rt] = *(const s16x8*)&Ys[rt*16+lr][(kt+1)*32 + lq*8];
        }
        if (kt < 6){
          #pragma unroll
          for (int ct=0;ct<4;ct++) bn[ct] = W2v[(size_t)((kt+2)*16 + wv*4 + ct)*64 + l];
        }
        #pragma unroll
        for (int rt=0; rt<4; rt++)
          #pragma unroll
          for (int ct=0; ct<4; ct++)
            acc2[rt][ct] = __builtin_amdgcn_mfma_f32_16x16x32_bf16(a0[rt], b0[ct], acc2[rt][ct], 0,0,0);
        #pragma unroll
        for (int i=0;i<4;i++){ a0[i]=an[i]; b0[i]=b1[i]; b1[i]=bn[i]; }
      }
    }

    if (FINAL){
      if (dir==0){
        #pragma unroll
        for (int rt=0; rt<4; rt++)
          #pragma unroll
          for (int ct=0; ct<4; ct++) fsv[rt][ct] = acc2[rt][ct];
      } else {
        #pragma unroll
        for (int rt=0; rt<4; rt++)
          #pragma unroll
          for (int ct=0; ct<4; ct++)
            #pragma unroll
            for (int r=0; r<4; r++){
              int row = e0 + rt*16 + lq*4 + r;
              outp[(size_t)row*MSGD + cbase + ct*16 + lr] = fsv[rt][ct][r] + acc2[rt][ct][r];
            }
      }
    } else {
      const int* gidx = dir ? sidx : didx;
      #pragma unroll
      for (int rt=0; rt<4; rt++)
        #pragma unroll
        for (int ct=0; ct<4; ct++)
          #pragma unroll
          for (int r=0; r<4; r++){
            int row = rt*16 + lq*4 + r;
            atomicAdd(&outp[(size_t)gidx[row]*MSGD + cbase + ct*16 + lr], acc2[rt][ct][r]);
          }
    }
    __syncthreads();
  }
}

// ---------------- GRU, bf16 MFMA, gate-aligned column tiles ----------------
__global__ void __launch_bounds__(256,2) k_gru(const float* __restrict__ h,
    const float* __restrict__ agg,
    const short* __restrict__ wih_p, const float* __restrict__ bih,
    const short* __restrict__ whh_p, const float* __restrict__ bhh,
    float* __restrict__ hnew){
  __shared__ __align__(16) short aggs[64][264];
  __shared__ __align__(16) short hs[64][136];
  int t = threadIdx.x;
  int n0 = blockIdx.x*64;
  for (int i=t; i<64*32; i+=256){
    int r = i>>5, c8 = (i&31)*8;
    float4 a = *(const float4*)&agg[(size_t)(n0+r)*MSGD + c8];
    float4 b = *(const float4*)&agg[(size_t)(n0+r)*MSGD + c8 + 4];
    s16x8 v;
    v[0]=f2bf(a.x); v[1]=f2bf(a.y); v[2]=f2bf(a.z); v[3]=f2bf(a.w);
    v[4]=f2bf(b.x); v[5]=f2bf(b.y); v[6]=f2bf(b.z); v[7]=f2bf(b.w);
    *(s16x8*)&aggs[r][c8] = v;
  }
  for (int i=t; i<64*16; i+=256){
    int r = i>>4, c8 = (i&15)*8;
    float4 a = *(const float4*)&h[(size_t)(n0+r)*HD + c8];
    float4 b = *(const float4*)&h[(size_t)(n0+r)*HD + c8 + 4];
    s16x8 v;
    v[0]=f2bf(a.x); v[1]=f2bf(a.y); v[2]=f2bf(a.z); v[3]=f2bf(a.w);
    v[4]=f2bf(b.x); v[5]=f2bf(b.y); v[6]=f2bf(b.z); v[7]=f2bf(b.w);
    *(s16x8*)&hs[r][c8] = v;
  }
  __syncthreads();

  int wv = t>>6, l = t&63, lr = l&15, lq = l>>4;
  const s16x8* Wih_v = (const s16x8*)wih_p;
  const s16x8* Whh_v = (const s16x8*)whh_p;

  f32x4 gi[4][6], gh[4][6];
  #pragma unroll
  for (int ct=0; ct<6; ct++){
    int bcol = (ct>>1)*128 + wv*32 + (ct&1)*16 + lr;
    float bi = bih[bcol], bh = bhh[bcol];
    #pragma unroll
    for (int rt=0; rt<4; rt++){
      gi[rt][ct] = (f32x4){bi,bi,bi,bi};
      gh[rt][ct] = (f32x4){bh,bh,bh,bh};
    }
  }
  for (int kt=0; kt<8; kt++){
    s16x8 af[4], bfr[6];
    #pragma unroll
    for (int rt=0; rt<4; rt++) af[rt] = *(const s16x8*)&aggs[rt*16+lr][kt*32 + lq*8];
    #pragma unroll
    for (int ct=0; ct<6; ct++){
      int nt = (ct>>1)*8 + wv*2 + (ct&1);
      bfr[ct] = Wih_v[(size_t)(kt*24 + nt)*64 + l];
    }
    #pragma unroll
    for (int rt=0; rt<4; rt++)
      #pragma unroll
      for (int ct=0; ct<6; ct++)
        gi[rt][ct] = __builtin_amdgcn_mfma_f32_16x16x32_bf16(af[rt], bfr[ct], gi[rt][ct], 0,0,0);
  }
  for (int kt=0; kt<4; kt++){
    s16x8 af[4], bfr[6];
    #pragma unroll
    for (int rt=0; rt<4; rt++) af[rt] = *(const s16x8*)&hs[rt*16+lr][kt*32 + lq*8];
    #pragma unroll
    for (int ct=0; ct<6; ct++){
      int nt = (ct>>1)*8 + wv*2 + (ct&1);
      bfr[ct] = Whh_v[(size_t)(kt*24 + nt)*64 + l];
    }
    #pragma unroll
    for (int rt=0; rt<4; rt++)
      #pragma unroll
      for (int ct=0; ct<6; ct++)
        gh[rt][ct] = __builtin_amdgcn_mfma_f32_16x16x32_bf16(af[rt], bfr[ct], gh[rt][ct], 0,0,0);
  }
  #pragma unroll
  for (int rt=0; rt<4; rt++)
    #pragma unroll
    for (int j=0; j<2; j++)
      #pragma unroll
      for (int r=0; r<4; r++){
        int row = n0 + rt*16 + lq*4 + r;
        int col = wv*32 + j*16 + lr;
        float rr = 1.f/(1.f + __expf(-(gi[rt][j][r]   + gh[rt][j][r])));
        float zz = 1.f/(1.f + __expf(-(gi[rt][2+j][r] + gh[rt][2+j][r])));
        float gn = gi[rt][4+j][r] + rr*gh[rt][4+j][r];
        float nn = 1.f - 2.f/(__expf(2.f*gn) + 1.f);   // tanh
        float hold = h[(size_t)row*HD + col];
        hnew[(size_t)row*HD + col] = (1.f - zz)*nn + zz*hold;
      }
}

// ---------------- SK transform ----------------
__global__ void __launch_bounds__(256) k_tall(const float* __restrict__ ef,
    const float* __restrict__ W1, const float* __restrict__ b1,
    const float* __restrict__ W2, const float* __restrict__ b2,
    float* __restrict__ tall){
  __shared__ float W1s[256*32];
  __shared__ float W2s[32*32];
  __shared__ float b1s[32], b2s[32];
  __shared__ float xsr[8][256];
  __shared__ float y1s[8][32];
  int t = threadIdx.x;
  for (int i=t;i<256*32;i+=256) W1s[i]=W1[i];
  for (int i=t;i<32*32;i+=256)  W2s[i]=W2[i];
  if (t<32){ b1s[t]=b1[t]; b2s[t]=b2[t]; }
  int g = blockIdx.x >> 5;
  int i0 = (blockIdx.x & 31)*8;
  for (int i=t;i<8*256;i+=256){
    int r = i>>8, k = i&255;
    int row = i0+r;
    xsr[r][k] = (row < EPG) ? ef[((size_t)g*EPG + row)*MSGD + k] : 0.f;
  }
  __syncthreads();
  int r = t>>5, c = t&31;
  float acc = b1s[c];
  for (int k=0;k<256;k+=4){
    const float4 x4 = *(const float4*)&xsr[r][k];
    acc = fmaf(x4.x,W1s[(k+0)*32+c], fmaf(x4.y,W1s[(k+1)*32+c],
          fmaf(x4.z,W1s[(k+2)*32+c], fmaf(x4.w,W1s[(k+3)*32+c], acc))));
  }
  y1s[r][c] = fmaxf(acc, 0.f);
  __syncthreads();
  float acc2 = b2s[c];
  #pragma unroll
  for (int k=0;k<32;k++) acc2 = fmaf(y1s[r][k], W2s[k*32+c], acc2);
  int row = i0+r;
  tall[((size_t)g*256 + row)*SKD + c] = (row < EPG) ? acc2 : 0.f;
}

// ---------------- la init ----------------
__global__ void __launch_bounds__(256) k_lainit(const float* __restrict__ tall,
    float* __restrict__ la){
  __shared__ float tqs[256*32];
  __shared__ float tcs[256*32];
  int p = blockIdx.x, t = threadIdx.x;
  const float* tq = tall + (size_t)(2*p)*8192;
  const float* tc = tall + (size_t)(2*p+1)*8192;
  for (int i=t;i<8192;i+=256){ tqs[i]=tq[i]; tcs[i]=tc[i]; }
  __syncthreads();
  float creg[32];
  #pragma unroll
  for (int k=0;k<32;k++) creg[k]=tcs[t*32+k];
  float* out = la + (size_t)p*65536;
  for (int i=0;i<256;i++){
    float acc = 0.f;
    #pragma unroll
    for (int k=0;k<32;k+=4){
      const float4 q4 = *(const float4*)&tqs[i*32+k];
      acc = fmaf(q4.x,creg[k], fmaf(q4.y,creg[k+1], fmaf(q4.z,creg[k+2], fmaf(q4.w,creg[k+3], acc))));
    }
    out[(size_t)i*256 + t] = acc * 10.0f;
  }
}

// ---------------- Sinkhorn: register-resident, shift-based LSE ----------------
// r/c reformulation with running shifts: after any col pass, A - r - c <= 0,
// so r_old / c_old are overflow-safe LSE shifts (s in [1/256, 256] provably).
// Only iteration 0's row pass needs a true max. r kept in registers (wave-uniform).
__global__ void __launch_bounds__(1024) k_sinkhorn(float* __restrict__ la){
  __shared__ float cv[256];
  __shared__ float psm[16][256];
  int t = threadIdx.x;
  int w = t>>6, l = t&63;
  int rbase = w*16;
  float* A = la + (size_t)blockIdx.x*65536;
  float4 Areg[16];
  #pragma unroll
  for (int k=0;k<16;k++)
    Areg[k] = *(const float4*)&A[(size_t)(rbase+k)*256 + 4*l];
  if (t < 256) cv[t] = 0.f;
  float r[16];
  // ---- iteration 0 row pass: true max (A can be ~±300) ----
  #pragma unroll
  for (int k=0;k<16;k++){
    float4 v = Areg[k];
    float m = fmaxf(fmaxf(v.x,v.y), fmaxf(v.z,v.w));
    #pragma unroll
    for (int off=32; off; off>>=1) m = fmaxf(m, __shfl_xor(m, off));
    float s = __expf(v.x-m)+__expf(v.y-m)+__expf(v.z-m)+__expf(v.w-m);
    #pragma unroll
    for (int off=32; off; off>>=1) s += __shfl_xor(s, off);
    r[k] = m + __logf(s);
  }
  __syncthreads();

  for (int it=0; it<20; it++){
    // ---- col pass: c += log(sum_i exp(A - r - c)), args <= 0 ----
    float4 c4 = *(const float4*)&cv[4*l];
    float4 sm = {0.f,0.f,0.f,0.f};
    #pragma unroll
    for (int k=0;k<16;k++){
      float rk = r[k];
      sm.x += __expf(Areg[k].x - rk - c4.x);
      sm.y += __expf(Areg[k].y - rk - c4.y);
      sm.z += __expf(Areg[k].z - rk - c4.z);
      sm.w += __expf(Areg[k].w - rk - c4.w);
    }
    *(float4*)&psm[w][4*l] = sm;
    __syncthreads();
    if (t < 256){
      float s = psm[0][t];
      #pragma unroll
      for (int ww=1; ww<16; ww++) s += psm[ww][t];
      cv[t] += __logf(s);
    }
    __syncthreads();
    // ---- row pass for next iteration: r += log(sum_j exp(A - c - r)) ----
    if (it < 19){
      float4 cn = *(const float4*)&cv[4*l];
      #pragma unroll
      for (int k=0;k<16;k++){
        float rk = r[k];
        float s = __expf(Areg[k].x - cn.x - rk) + __expf(Areg[k].y - cn.y - rk)
                + __expf(Areg[k].z - cn.z - rk) + __expf(Areg[k].w - cn.w - rk);
        #pragma unroll
        for (int off=32; off; off>>=1) s += __shfl_xor(s, off);
        r[k] = rk + __logf(s);
      }
    }
  }
  // ---- plan = exp(A - r - c), in place ----
  float4 c4 = *(const float4*)&cv[4*l];
  #pragma unroll
  for (int k=0;k<16;k++){
    float rk = r[k];
    float4 p;
    p.x = __expf(Areg[k].x - rk - c4.x);
    p.y = __expf(Areg[k].y - rk - c4.y);
    p.z = __expf(Areg[k].z - rk - c4.z);
    p.w = __expf(Areg[k].w - rk - c4.w);
    *(float4*)&A[(size_t)(rbase+k)*256 + 4*l] = p;
  }
}

// ---------------- loss: -sum relu(q - plan @ c) ----------------
__global__ void __launch_bounds__(256) k_loss(const float* __restrict__ plan,
    const float* __restrict__ ef, float* __restrict__ out){
  __shared__ float ps[32][32];
  __shared__ float cs[32][256];
  __shared__ float red[4];
  int bid = blockIdx.x;
  int p = bid>>3, i0 = (bid&7)*32;
  int t = threadIdx.x;
  float acc[32];
  #pragma unroll
  for (int r=0;r<32;r++) acc[r]=0.f;
  const float* lap  = plan + (size_t)p*65536;
  const float* crow = ef + (size_t)(2*p+1)*EPG*MSGD;
  for (int kt=0; kt<EPG; kt+=32){
    __syncthreads();
    for (int i=t;i<32*32;i+=256){
      int r = i>>5, k = i&31;
      ps[r][k] = (kt+k < EPG) ? lap[(size_t)(i0+r)*256 + kt+k] : 0.f;
    }
    for (int i=t;i<32*256;i+=256){
      int k = i>>8, f = i&255;
      cs[k][f] = (kt+k < EPG) ? crow[(size_t)(kt+k)*MSGD + f] : 0.f;
    }
    __syncthreads();
    for (int k=0;k<32;k++){
      float cv = cs[k][t];
      #pragma unroll
      for (int r=0;r<32;r++) acc[r] = fmaf(ps[r][k], cv, acc[r]);
    }
  }
  const float* qrow = ef + (size_t)(2*p)*EPG*MSGD;
  float s = 0.f;
  #pragma unroll
  for (int r=0;r<32;r++){
    int row = i0+r;
    float q = (row < EPG) ? qrow[(size_t)row*MSGD + t] : 0.f;
    s += fmaxf(q - acc[r], 0.f);
  }
  #pragma unroll
  for (int off=32; off; off>>=1) s += __shfl_xor(s, off);
  if ((t&63)==0) red[t>>6]=s;
  __syncthreads();
  if (t==0) atomicAdd(&out[p], -(red[0]+red[1]+red[2]+red[3]));
}

// ---------------- launch ----------------
extern "C" void kernel_launch(void* const* d_in, const int* in_sizes, int n_in,
                              void* d_out, int out_size, void* d_ws, size_t ws_size,
                              hipStream_t stream){
  const float* nf   = (const float*)d_in[0];
  const float* ef   = (const float*)d_in[1];
  const int*   fidx = (const int*)d_in[2];
  const int*   tidx = (const int*)d_in[3];
  const float* enw  = (const float*)d_in[4];
  const float* enb  = (const float*)d_in[5];
  const float* eew  = (const float*)d_in[6];
  const float* eeb  = (const float*)d_in[7];
  const float* mw1  = (const float*)d_in[8];
  const float* mb1  = (const float*)d_in[9];
  const float* mw2  = (const float*)d_in[10];
  const float* mb2  = (const float*)d_in[11];
  const float* rw1  = (const float*)d_in[12];
  const float* rb1  = (const float*)d_in[13];
  const float* rw2  = (const float*)d_in[14];
  const float* rb2  = (const float*)d_in[15];
  const float* wih  = (const float*)d_in[16];
  const float* bih  = (const float*)d_in[17];
  const float* whh  = (const float*)d_in[18];
  const float* bhh  = (const float*)d_in[19];
  const float* skw1 = (const float*)d_in[20];
  const float* skb1 = (const float*)d_in[21];
  const float* skw2 = (const float*)d_in[22];
  const float* skb2 = (const float*)d_in[23];
  float* out = (float*)d_out;

  float* ws = (float*)d_ws;
  float* h_a    = ws;
  float* h_b    = h_a + (size_t)NN*HD;
  float* e_enc  = h_b + (size_t)NN*HD;
  float* e_fin  = e_enc + (size_t)NE*EED;
  float* agg    = e_fin;                           // aliases e_fin (loop phase only)
  float* t_all  = e_fin + (size_t)NE*MSGD;
  float* la     = t_all + (size_t)NG*256*SKD;

  // packed bf16 weights alias la (la written only after all k_msg/k_gru done)
  short* w1f_p = (short*)la;
  short* w1r_p = w1f_p + 320*256;
  short* w2f_p = w1r_p + 320*256;
  short* w2r_p = w2f_p + 256*256;
  short* wih_p = w2r_p + 256*256;
  short* whh_p = wih_p + 256*384;

  k_pack<<<40, 256, 0, stream>>>(mw1, w1f_p, 320, 256);
  k_pack<<<40, 256, 0, stream>>>(rw1, w1r_p, 320, 256);
  k_pack<<<32, 256, 0, stream>>>(mw2, w2f_p, 256, 256);
  k_pack<<<32, 256, 0, stream>>>(rw2, w2r_p, 256, 256);
  k_pack<<<48, 256, 0, stream>>>(wih, wih_p, 256, 384);
  k_pack<<<24, 256, 0, stream>>>(whh, whh_p, 128, 384);

  k_enc_node<<<NN/2, 256, 0, stream>>>(nf, enw, enb, h_a);
  k_enc_edge<<<NE/4, 256, 0, stream>>>(ef, eew, eeb, e_enc);

  float* hc = h_a; float* hn = h_b;
  for (int step=0; step<5; step++){
    hipMemsetAsync(agg, 0, (size_t)NN*MSGD*sizeof(float), stream);
    k_msg<false><<<NE/64, 256, 0, stream>>>(hc, e_enc, fidx, tidx,
        w1f_p, mb1, w2f_p, mb2, w1r_p, rb1, w2r_p, rb2, agg);
    k_gru<<<NN/64, 256, 0, stream>>>(hc, agg, wih_p, bih, whh_p, bhh, hn);
    float* tmp = hc; hc = hn; hn = tmp;
  }
  k_msg<true><<<NE/64, 256, 0, stream>>>(hc, e_enc, fidx, tidx,
      w1f_p, mb1, w2f_p, mb2, w1r_p, rb1, w2r_p, rb2, e_fin);

  k_tall<<<NG*32, 256, 0, stream>>>(e_fin, skw1, skb1, skw2, skb2, t_all);
  k_lainit<<<NP, 256, 0, stream>>>(t_all, la);
  k_sinkhorn<<<NP, 1024, 0, stream>>>(la);

  hipMemsetAsync(out, 0, (size_t)NP*sizeof(float), stream);
  k_loss<<<NP*8, 256, 0, stream>>>(la, e_fin, out);
}